// Round 10
// baseline (960.020 us; speedup 1.0000x reference)
//
#include <hip/hip_runtime.h>
#include <math.h>

// ---------------- model dims ----------------
constexpr int N_NODES = 16384;
constexpr int BGRAPH  = 64;
constexpr int NEDGE   = 524288;
constexpr int SEQ     = 257;           // NPG + cls
constexpr int WDIM    = 256;
constexpr int DFF     = 1024;
constexpr int HID     = 512;
constexpr int MROWS   = BGRAPH * SEQ;  // 16448 = 257*64 exactly

// ---------------- ws layout (float offsets for fp32 region) ----------------
constexpr size_t F_Y    = 0;                                   // [N,64]
constexpr size_t F_AGG  = F_Y    + (size_t)N_NODES * 64;       // [N,64]
constexpr size_t F_XD   = F_AGG  + (size_t)N_NODES * 64;       // [16448,256] residual (fp32)
constexpr size_t F_CLS  = F_XD   + (size_t)MROWS * WDIM;       // [64,256]
constexpr size_t F_D1   = F_CLS  + (size_t)BGRAPH * WDIM;      // [64,512]
constexpr size_t F_D2   = F_D1   + (size_t)BGRAPH * HID;       // [64,512]
constexpr size_t F_WPAD = F_D2   + (size_t)BGRAPH * HID;       // [64,256]
constexpr size_t F_DINV = F_WPAD + (size_t)64 * WDIM;          // [N]
constexpr size_t F_IEND = F_DINV + (size_t)N_NODES;

typedef __attribute__((ext_vector_type(8))) __bf16 bf16x8;
typedef __attribute__((ext_vector_type(4))) __bf16 bf16x4;
typedef __attribute__((ext_vector_type(4))) float f32x4;

__device__ __forceinline__ float gelu_f(float x) {
    float u = 0.7978845608028654f * (x + 0.044715f * x * x * x);
    return 0.5f * x * (1.0f + tanhf(u));
}

// ---------------- GCN prelude ----------------
__global__ __launch_bounds__(256) void hist_kernel(const int* __restrict__ col, int* __restrict__ indeg) {
    int e = blockIdx.x * 256 + threadIdx.x;
    atomicAdd(&indeg[col[e]], 1);
}

__global__ __launch_bounds__(1024) void scan_kernel(const int* __restrict__ indeg, int* __restrict__ offs,
                                                    int* __restrict__ cursor, float* __restrict__ dinv) {
    __shared__ int parts[1024];
    int t = threadIdx.x;
    int base = t * 16;
    int loc[16];
    int s = 0;
#pragma unroll
    for (int i = 0; i < 16; ++i) { loc[i] = indeg[base + i]; s += loc[i]; }
    parts[t] = s;
    __syncthreads();
    for (int off = 1; off < 1024; off <<= 1) {
        int v = (t >= off) ? parts[t - off] : 0;
        __syncthreads();
        parts[t] += v;
        __syncthreads();
    }
    int run = (t == 0) ? 0 : parts[t - 1];
#pragma unroll
    for (int i = 0; i < 16; ++i) {
        offs[base + i] = run;
        cursor[base + i] = run;
        dinv[base + i] = rsqrtf((float)loc[i] + 1.0f);  // deg = indeg + self-loop
        run += loc[i];
    }
    if (t == 1023) offs[N_NODES] = run;
}

__global__ __launch_bounds__(256) void fill_kernel(const int* __restrict__ ei, int* __restrict__ cursor,
                                                   int* __restrict__ csr) {
    int e = blockIdx.x * 256 + threadIdx.x;
    int r = ei[e];            // source
    int c = ei[NEDGE + e];    // destination
    int pos = atomicAdd(&cursor[c], 1);
    csr[pos] = r;
}

// xc = [x(32) | sin(p*2^j*pi)(24) | 0(8)], pre-scaled by dinv[node]
__global__ __launch_bounds__(256) void y_kernel(const float* __restrict__ x, const float* __restrict__ p,
                                                const float* __restrict__ dinv, float* __restrict__ y) {
    int idx = blockIdx.x * 256 + threadIdx.x;
    int i = idx >> 6, d = idx & 63;
    float v = 0.f;
    if (d < 32) {
        v = x[i * 32 + d];
    } else if (d < 56) {
        int dd = d - 32;
        int dim = dd >> 3, j = dd & 7;
        v = sinf(p[i * 3 + dim] * (3.14159265358979323846f * (float)(1 << j)));
    }
    y[idx] = dinv[i] * v;
}

// agg[c] = dinv[c] * (y[c] + sum_{in-edges} y[src])   (wave per node)
__global__ __launch_bounds__(256) void agg_kernel(const float* __restrict__ y, const float* __restrict__ dinv,
                                                  const int* __restrict__ offs, const int* __restrict__ csr,
                                                  float* __restrict__ agg) {
    int c = (blockIdx.x * 256 + threadIdx.x) >> 6;
    int lane = threadIdx.x & 63;
    float acc = y[(size_t)c * 64 + lane];
    int s = offs[c], e = offs[c + 1];
    for (int j = s; j < e; ++j) {
        int r = csr[j];
        acc += y[(size_t)r * 64 + lane];
    }
    agg[(size_t)c * 64 + lane] = dinv[c] * acc;
}

__global__ __launch_bounds__(256) void wpad_kernel(const float* __restrict__ w, float* __restrict__ wp) {
    int idx = blockIdx.x * 256 + threadIdx.x;
    wp[idx] = (idx < 56 * 256) ? w[idx] : 0.f;
}

__global__ __launch_bounds__(256) void cls_write(const float* __restrict__ tok, float* __restrict__ xd) {
    xd[(size_t)blockIdx.x * SEQ * WDIM + threadIdx.x] = tok[threadIdx.x];
}

// ---------------- LayerNorm: wave per row, 4 rows/block, no barriers ----------------
template <int OUTBF>
__global__ __launch_bounds__(256) void ln4_kernel(const float* __restrict__ in, int rin_stride,
                                                  void* __restrict__ out,
                                                  const float* __restrict__ g, const float* __restrict__ be) {
    int w = threadIdx.x >> 6, lane = threadIdx.x & 63;
    int row = blockIdx.x * 4 + w;
    const float* ip = in + (size_t)row * rin_stride + lane * 4;
    f32x4 v = *(const f32x4*)ip;
    float s = v[0] + v[1] + v[2] + v[3];
    float ss = v[0] * v[0] + v[1] * v[1] + v[2] * v[2] + v[3] * v[3];
#pragma unroll
    for (int off = 1; off < 64; off <<= 1) { s += __shfl_xor(s, off); ss += __shfl_xor(ss, off); }
    float mean = s * 0.00390625f;
    float var = ss * 0.00390625f - mean * mean;
    float rs = rsqrtf(var + 1e-5f);
    f32x4 gv = *(const f32x4*)(g + lane * 4);
    f32x4 bv = *(const f32x4*)(be + lane * 4);
    if (OUTBF) {
        bf16x4 o;
#pragma unroll
        for (int i = 0; i < 4; ++i) o[i] = (__bf16)((v[i] - mean) * rs * gv[i] + bv[i]);
        *(bf16x4*)((__bf16*)out + (size_t)row * 256 + lane * 4) = o;
    } else {
        f32x4 o;
#pragma unroll
        for (int i = 0; i < 4; ++i) o[i] = (v[i] - mean) * rs * gv[i] + bv[i];
        *(f32x4*)((float*)out + (size_t)row * 256 + lane * 4) = o;
    }
}

// ---------------- weight transpose+cast: W[K][N] fp32 -> Wt[N][K] bf16 ----------------
__global__ __launch_bounds__(256) void tcast_kernel(const float* __restrict__ W, __bf16* __restrict__ Wt,
                                                    int K, int N) {
    __shared__ __bf16 T[64][65];
    int t = threadIdx.x;
    int k0 = blockIdx.x << 6, n0 = blockIdx.y << 6;
#pragma unroll
    for (int i = 0; i < 16; ++i) {
        int idx = t + i * 256;
        int k = idx >> 6, n = idx & 63;
        T[k][n] = (__bf16)W[(size_t)(k0 + k) * N + n0 + n];
    }
    __syncthreads();
#pragma unroll
    for (int i = 0; i < 16; ++i) {
        int idx = t + i * 256;
        int n = idx >> 6, k = idx & 63;
        Wt[(size_t)(n0 + n) * K + k0 + k] = T[k][n];
    }
}

// ---------------- bf16 MFMA GEMM v2: BM=64, BN in {64,128} ----------------
// High-TLP variant: grids of 1000-2100 blocks (4-8/CU) so cross-block MFMA issue
// covers each block's barrier drain (m114 overlap). Static even/odd prefetch
// registers (round-8 lesson: NO dynamically-indexed reg arrays -> no scratch).
// Vectorized epilogue: acc -> LDS tile (padded pitch) -> coalesced bf16x8/f32x4
// global stores; OMODE=1 reads residual as f32x4. M must = 257*64 (no guards).
// 1D grid, XCD swizzle: y-blocks of one m-group share blockIdx%8 -> same XCD L2.
// OMODE 0: bf16 store. OMODE 1: fp32 store += resid. K multiple of 64.
constexpr int LP = 36;
template <int BN, int ACT, int OMODE>
__global__ __launch_bounds__(256) void gemm_v2(const __bf16* __restrict__ A, int lda,
                                               const __bf16* __restrict__ Bt,
                                               const float* __restrict__ bias,
                                               void* __restrict__ Cv, int ldc,
                                               int Ktot, int MBlocks, int NY) {
    constexpr int NTW = BN / 32;                 // n-tiles per wave (wave tile 32 x BN/2)
    constexpr int CP  = OMODE ? (BN + 8) : (BN + 8);   // padded epilogue pitch
    constexpr size_t S_STAGE = (size_t)(64 + BN) * LP * sizeof(__bf16);
    constexpr size_t S_EPI   = (size_t)64 * CP * (OMODE ? sizeof(float) : sizeof(__bf16));
    constexpr size_t S_LDS   = S_STAGE > S_EPI ? S_STAGE : S_EPI;
    __shared__ __align__(16) char lds_raw[S_LDS];
    __bf16* As = (__bf16*)lds_raw;
    __bf16* Bs = As + 64 * LP;

    // swizzle decode: f = (m%8) + 8*(y + NY*(m/8))
    int f = blockIdx.x;
    int m8 = f & 7;
    int rest = f >> 3;
    int mg = rest / NY;
    int yb = rest - mg * NY;
    int mb = mg * 8 + m8;
    if (mb >= MBlocks) return;
    int m0 = mb << 6, n0 = yb * BN;

    int t = threadIdx.x;
    int w = t >> 6, L = t & 63;
    int wm = w >> 1, wn = w & 1;
    int lc = L & 15, quad = L >> 4;

    // A staging: thread -> row t>>2 (64 rows), 8-elem chunk (t&3)*8 -> one bf16x8
    int sa_row = t >> 2, sa_off = (t & 3) << 3;
    const __bf16* ap = A + (size_t)(m0 + sa_row) * lda + sa_off;
    __bf16* as_dst = &As[sa_row * LP + sa_off];
    const __bf16* bp;
    __bf16* bs_dst;
    if constexpr (BN == 128) {
        int sb_row = t >> 1, sb_off = (t & 1) << 4;   // two bf16x8 per thread
        bp = Bt + (size_t)(n0 + sb_row) * Ktot + sb_off;
        bs_dst = &Bs[sb_row * LP + sb_off];
    } else {
        bp = Bt + (size_t)(n0 + sa_row) * Ktot + sa_off;  // one bf16x8 per thread
        bs_dst = &Bs[sa_row * LP + sa_off];
    }

    int a_base = (wm * 32 + lc) * LP + quad * 8;
    int b_base = (wn * (BN / 2) + lc) * LP + quad * 8;

    f32x4 acc[2][NTW] = {};

    // even (k0) / odd (k0+32) prefetch registers — statically named
    bf16x8 eA, oA, eB0, eB1, oB0, oB1;
    eA = *(const bf16x8*)(ap);
    oA = *(const bf16x8*)(ap + 32);
    eB0 = *(const bf16x8*)(bp);
    oB0 = *(const bf16x8*)(bp + 32);
    if constexpr (BN == 128) {
        eB1 = *(const bf16x8*)(bp + 8);
        oB1 = *(const bf16x8*)(bp + 40);
    }

    for (int k0 = 0; k0 < Ktot; k0 += 64) {
        // ---- sub-step A: tile k0 ----
        __syncthreads();
        *(bf16x8*)as_dst = eA;
        *(bf16x8*)bs_dst = eB0;
        if constexpr (BN == 128) *(bf16x8*)(bs_dst + 8) = eB1;
        __syncthreads();
        if (k0 + 64 < Ktot) {
            eA = *(const bf16x8*)(ap + k0 + 64);
            eB0 = *(const bf16x8*)(bp + k0 + 64);
            if constexpr (BN == 128) eB1 = *(const bf16x8*)(bp + k0 + 72);
        }
        {
            bf16x8 af[2], bfr[NTW];
#pragma unroll
            for (int i = 0; i < 2; ++i) af[i] = *(const bf16x8*)&As[a_base + i * 16 * LP];
#pragma unroll
            for (int i = 0; i < NTW; ++i) bfr[i] = *(const bf16x8*)&Bs[b_base + i * 16 * LP];
#pragma unroll
            for (int mt = 0; mt < 2; ++mt)
#pragma unroll
                for (int nt = 0; nt < NTW; ++nt)
                    acc[mt][nt] = __builtin_amdgcn_mfma_f32_16x16x32_bf16(af[mt], bfr[nt], acc[mt][nt], 0, 0, 0);
        }
        // ---- sub-step B: tile k0+32 ----
        __syncthreads();
        *(bf16x8*)as_dst = oA;
        *(bf16x8*)bs_dst = oB0;
        if constexpr (BN == 128) *(bf16x8*)(bs_dst + 8) = oB1;
        __syncthreads();
        if (k0 + 96 < Ktot) {
            oA = *(const bf16x8*)(ap + k0 + 96);
            oB0 = *(const bf16x8*)(bp + k0 + 96);
            if constexpr (BN == 128) oB1 = *(const bf16x8*)(bp + k0 + 104);
        }
        {
            bf16x8 af[2], bfr[NTW];
#pragma unroll
            for (int i = 0; i < 2; ++i) af[i] = *(const bf16x8*)&As[a_base + i * 16 * LP];
#pragma unroll
            for (int i = 0; i < NTW; ++i) bfr[i] = *(const bf16x8*)&Bs[b_base + i * 16 * LP];
#pragma unroll
            for (int mt = 0; mt < 2; ++mt)
#pragma unroll
                for (int nt = 0; nt < NTW; ++nt)
                    acc[mt][nt] = __builtin_amdgcn_mfma_f32_16x16x32_bf16(af[mt], bfr[nt], acc[mt][nt], 0, 0, 0);
        }
    }

    // ---- epilogue: stage in LDS, vectorized global I/O ----
    __syncthreads();   // done with As/Bs; lds_raw becomes the C tile
    if constexpr (OMODE == 0) {
        __bf16* Cs = (__bf16*)lds_raw;
#pragma unroll
        for (int mt = 0; mt < 2; ++mt) {
            int rl = wm * 32 + mt * 16 + quad * 4;
#pragma unroll
            for (int nt = 0; nt < NTW; ++nt) {
                int cl = wn * (BN / 2) + nt * 16 + lc;
                float bv = bias[n0 + cl];
#pragma unroll
                for (int r = 0; r < 4; ++r) {
                    float v = acc[mt][nt][r] + bv;
                    if (ACT == 1) v = gelu_f(v);
                    Cs[(rl + r) * CP + cl] = (__bf16)v;
                }
            }
        }
        __syncthreads();
        constexpr int VPT = BN / 32;        // bf16x8 vectors per thread (64*BN/8/256)
#pragma unroll
        for (int i = 0; i < VPT; ++i) {
            int idx = t + i * 256;
            int row = idx / (BN / 8), c8 = idx % (BN / 8);
            bf16x8 v = *(const bf16x8*)&Cs[row * CP + c8 * 8];
            *(bf16x8*)((__bf16*)Cv + (size_t)(m0 + row) * ldc + n0 + c8 * 8) = v;
        }
    } else {
        float* Cs = (float*)lds_raw;
#pragma unroll
        for (int mt = 0; mt < 2; ++mt) {
            int rl = wm * 32 + mt * 16 + quad * 4;
#pragma unroll
            for (int nt = 0; nt < NTW; ++nt) {
                int cl = wn * (BN / 2) + nt * 16 + lc;
                float bv = bias[n0 + cl];
#pragma unroll
                for (int r = 0; r < 4; ++r) {
                    float v = acc[mt][nt][r] + bv;
                    if (ACT == 1) v = gelu_f(v);
                    Cs[(rl + r) * CP + cl] = v;
                }
            }
        }
        __syncthreads();
        constexpr int VPT = BN / 16;        // f32x4 vectors per thread (64*BN/4/256)
#pragma unroll
        for (int i = 0; i < VPT; ++i) {
            int idx = t + i * 256;
            int row = idx / (BN / 4), c4 = idx % (BN / 4);
            float* gp = (float*)Cv + (size_t)(m0 + row) * ldc + n0 + c4 * 4;
            f32x4 oldv = *(const f32x4*)gp;
            f32x4 d = *(const f32x4*)&Cs[row * CP + c4 * 4];
            oldv[0] += d[0]; oldv[1] += d[1]; oldv[2] += d[2]; oldv[3] += d[3];
            *(f32x4*)gp = oldv;
        }
    }
}

// ---------------- MFMA attention on bf16 qkv; K-fragments hoisted to registers ----------------
constexpr int PPITCH = 284;  // 568 B rows: staging stores 2-way (free), frag reads conflict-free
__global__ __launch_bounds__(256, 2) void attn_mfma(const __bf16* __restrict__ qkvb,
                                                    __bf16* __restrict__ obuf) {
    __shared__ __bf16 Vt[32][PPITCH];        // Vt[d][key], keys 257..271 zeroed
    __shared__ __bf16 Pb[4][16][PPITCH];     // per-wave unnormalized P
    int bb = blockIdx.x;
    int b = bb >> 3, h = bb & 7;
    int t = threadIdx.x;
    int w = t >> 6, L = t & 63;
    int c = L & 15, quad = L >> 4;
    const float scale = 0.17677669529663687f;  // 1/sqrt(32)
    const __bf16* qb = qkvb + (size_t)(b * SEQ) * 768 + h * 32;
    const __bf16* kb = qb + 256;
    const __bf16* vb = qb + 512;
    __bf16* ob = obuf + (size_t)(b * SEQ) * 256 + h * 32;

    // stage V^T (vector load, scalar transpose-store)
    for (int idx = t; idx < 272 * 4; idx += 256) {
        int key = idx >> 2, dc = (idx & 3) * 8;
        bf16x8 vv = {};
        if (key < SEQ) vv = *(const bf16x8*)(vb + (size_t)key * 768 + dc);
#pragma unroll
        for (int j = 0; j < 8; ++j) Vt[dc + j][key] = vv[j];
    }

    // hoist ALL K-fragments into registers once (reused across every q-tile)
    bf16x8 kfr[17];
#pragma unroll
    for (int tt = 0; tt < 17; ++tt) {
        int kr = tt * 16 + c; if (kr > 256) kr = 256;
        kfr[tt] = *(const bf16x8*)(kb + (size_t)kr * 768 + quad * 8);
    }
    __syncthreads();

#pragma unroll 1
    for (int qt = 0; qt < 5; ++qt) {
        int q0 = qt * 64 + w * 16;
        if (q0 > 256) continue;
        int ntiles = (qt == 0 && w == 0) ? 17 : (qt * 4 + w + 1);
        if (ntiles > 17) ntiles = 17;
        int nkc = (ntiles + 1) >> 1;

        // Q fragment
        bf16x8 qf;
        {
            int qr = q0 + c; if (qr > 256) qr = 256;
            qf = *(const bf16x8*)(qb + (size_t)qr * 768 + quad * 8);
        }

        // QK^T (K from registers)
        f32x4 acc[17];
#pragma unroll
        for (int tt = 0; tt < 17; ++tt) {
            if (tt >= ntiles) continue;
            f32x4 z = {0.f, 0.f, 0.f, 0.f};
            acc[tt] = __builtin_amdgcn_mfma_f32_16x16x32_bf16(qf, kfr[tt], z, 0, 0, 0);
        }

        // masked softmax in C-layout
        float inv[4];
#pragma unroll
        for (int j = 0; j < 4; ++j) {
            int q = q0 + quad * 4 + j;
            float mx = -3.0e38f;
#pragma unroll
            for (int tt = 0; tt < 17; ++tt) {
                if (tt >= ntiles) continue;
                int key = tt * 16 + c;
                bool ok = (key < SEQ) && (q == 0 || key <= q);
                float v = ok ? acc[tt][j] * scale : -3.0e38f;
                mx = fmaxf(mx, v);
            }
            mx = fmaxf(mx, __shfl_xor(mx, 1));
            mx = fmaxf(mx, __shfl_xor(mx, 2));
            mx = fmaxf(mx, __shfl_xor(mx, 4));
            mx = fmaxf(mx, __shfl_xor(mx, 8));
            float s = 0.f;
#pragma unroll
            for (int tt = 0; tt < 17; ++tt) {
                if (tt >= ntiles) continue;
                int key = tt * 16 + c;
                bool ok = (key < SEQ) && (q == 0 || key <= q);
                float pv = ok ? expf(acc[tt][j] * scale - mx) : 0.f;
                s += pv;
                Pb[w][quad * 4 + j][key] = (__bf16)pv;
            }
            if ((ntiles & 1) && ntiles < 17)
                Pb[w][quad * 4 + j][ntiles * 16 + c] = (__bf16)0.f;
            s += __shfl_xor(s, 1);
            s += __shfl_xor(s, 2);
            s += __shfl_xor(s, 4);
            s += __shfl_xor(s, 8);
            inv[j] = 1.0f / s;
        }

        // PV
        f32x4 oacc0 = {0.f, 0.f, 0.f, 0.f};
        f32x4 oacc1 = {0.f, 0.f, 0.f, 0.f};
#pragma unroll
        for (int kc = 0; kc < 9; ++kc) {
            if (kc >= nkc) continue;
            int off = kc * 32 + quad * 8;
            bf16x8 af = {};
            bf16x8 bf0 = {};
            bf16x8 bf1 = {};
            if (off < 257) {
                af  = *(const bf16x8*)&Pb[w][c][off];
                bf0 = *(const bf16x8*)&Vt[c][off];
                bf1 = *(const bf16x8*)&Vt[16 + c][off];
            }
            oacc0 = __builtin_amdgcn_mfma_f32_16x16x32_bf16(af, bf0, oacc0, 0, 0, 0);
            oacc1 = __builtin_amdgcn_mfma_f32_16x16x32_bf16(af, bf1, oacc1, 0, 0, 0);
        }

        // epilogue: apply 1/sum, write bf16 O
#pragma unroll
        for (int j = 0; j < 4; ++j) {
            int q = q0 + quad * 4 + j;
            if (q < SEQ) {
                __bf16* op = ob + (size_t)q * 256;
                op[c]      = (__bf16)(oacc0[j] * inv[j]);
                op[16 + c] = (__bf16)(oacc1[j] * inv[j]);
            }
        }
    }
}

// ---------------- fp32 tiled GEMM (kept for GCN projection) ----------------
template <int ACT, bool RESID, bool REMAP>
__global__ __launch_bounds__(256) void gemm_std(const float* __restrict__ A, int lda,
                                                const float* __restrict__ Bw, int ldb,
                                                const float* __restrict__ bias,
                                                float* __restrict__ C, int ldc, int Ktot) {
    int t = threadIdx.x;
    int m0 = blockIdx.x << 6, n0 = blockIdx.y << 6;
    __shared__ float As[16][68];
    __shared__ float Bs[16][64];
    int arow = t >> 2, akk = (t & 3) << 2;
    int bk = t >> 4, bn = (t & 15) << 2;
    int tm = (t >> 4) << 2, tn = (t & 15) << 2;
    float acc[4][4] = {};
    const float* ap = A + (size_t)(m0 + arow) * lda + akk;
    const float* bp = Bw + (size_t)bk * ldb + n0 + bn;
    for (int k0 = 0; k0 < Ktot; k0 += 16) {
        float4 av = *(const float4*)(ap + k0);
        float4 bv = *(const float4*)(bp + (size_t)k0 * ldb);
        __syncthreads();
        As[akk + 0][arow] = av.x; As[akk + 1][arow] = av.y;
        As[akk + 2][arow] = av.z; As[akk + 3][arow] = av.w;
        *(float4*)&Bs[bk][bn] = bv;
        __syncthreads();
#pragma unroll
        for (int k = 0; k < 16; ++k) {
            float4 a = *(const float4*)&As[k][tm];
            float4 b = *(const float4*)&Bs[k][tn];
            acc[0][0] += a.x * b.x; acc[0][1] += a.x * b.y; acc[0][2] += a.x * b.z; acc[0][3] += a.x * b.w;
            acc[1][0] += a.y * b.x; acc[1][1] += a.y * b.y; acc[1][2] += a.y * b.z; acc[1][3] += a.y * b.w;
            acc[2][0] += a.z * b.x; acc[2][1] += a.z * b.y; acc[2][2] += a.z * b.z; acc[2][3] += a.z * b.w;
            acc[3][0] += a.w * b.x; acc[3][1] += a.w * b.y; acc[3][2] += a.w * b.z; acc[3][3] += a.w * b.w;
        }
    }
#pragma unroll
    for (int i = 0; i < 4; ++i) {
        int gm = m0 + tm + i;
        int orow = REMAP ? (gm + (gm >> 8) + 1) : gm;  // node -> xd row (skip cls slots)
        float* cp = C + (size_t)orow * ldc + n0 + tn;
        float4 r;
        r.x = acc[i][0] + bias[n0 + tn + 0];
        r.y = acc[i][1] + bias[n0 + tn + 1];
        r.z = acc[i][2] + bias[n0 + tn + 2];
        r.w = acc[i][3] + bias[n0 + tn + 3];
        if (ACT == 1) { r.x = gelu_f(r.x); r.y = gelu_f(r.y); r.z = gelu_f(r.z); r.w = gelu_f(r.w); }
        if (ACT == 2) { r.x = fmaxf(r.x, 0.f); r.y = fmaxf(r.y, 0.f); r.z = fmaxf(r.z, 0.f); r.w = fmaxf(r.w, 0.f); }
        if (RESID) {
            float4 o = *(const float4*)cp;
            r.x += o.x; r.y += o.y; r.z += o.z; r.w += o.w;
        }
        *(float4*)cp = r;
    }
}

// ---------------- decoder FC: grid (sample, out-chunk), 4 waves split K ----------------
template <int K, int NOUT>
__global__ __launch_bounds__(256) void dec_fc2(const float* __restrict__ in, const float* __restrict__ w,
                                               const float* __restrict__ bia, float* __restrict__ out) {
    __shared__ float rowbuf[K];
    __shared__ float part[4][64];
    int b = blockIdx.x, c = blockIdx.y, t = threadIdx.x;
    for (int i = t; i < K; i += 256) rowbuf[i] = in[(size_t)b * K + i];
    __syncthreads();
    int lane = t & 63, wv = t >> 6;
    int n = c * 64 + lane;
    const int KQ = K / 4;
    const float* wp = w + (size_t)(wv * KQ) * NOUT + n;
    float s = 0.f;
#pragma unroll 8
    for (int k = 0; k < KQ; ++k) s += rowbuf[wv * KQ + k] * wp[(size_t)k * NOUT];
    part[wv][lane] = s;
    __syncthreads();
    if (wv == 0) {
        float r = part[0][lane] + part[1][lane] + part[2][lane] + part[3][lane] + bia[n];
        out[(size_t)b * NOUT + n] = fmaxf(r, 0.f);
    }
}

// ---------------- launch ----------------
extern "C" void kernel_launch(void* const* d_in, const int* in_sizes, int n_in,
                              void* d_out, int out_size, void* d_ws, size_t ws_size,
                              hipStream_t stream) {
    const float* x         = (const float*)d_in[0];
    const float* p         = (const float*)d_in[1];
    const int*   ei        = (const int*)d_in[2];
    const float* gcn_w     = (const float*)d_in[4];
    const float* gcn_b     = (const float*)d_in[5];
    const float* cls_tok   = (const float*)d_in[6];
    const float* ln_pre_s  = (const float*)d_in[7];
    const float* ln_pre_b  = (const float*)d_in[8];
    const float* norm1_s   = (const float*)d_in[9];
    const float* norm1_b   = (const float*)d_in[10];
    const float* in_proj_w = (const float*)d_in[11];
    const float* in_proj_b = (const float*)d_in[12];
    const float* out_proj_w= (const float*)d_in[13];
    const float* out_proj_b= (const float*)d_in[14];
    const float* norm2_s   = (const float*)d_in[15];
    const float* norm2_b   = (const float*)d_in[16];
    const float* ff_w1     = (const float*)d_in[17];
    const float* ff_b1     = (const float*)d_in[18];
    const float* ff_w2     = (const float*)d_in[19];
    const float* ff_b2     = (const float*)d_in[20];
    const float* ln_post_s = (const float*)d_in[21];
    const float* ln_post_b = (const float*)d_in[22];
    const float* dec_w1    = (const float*)d_in[23];
    const float* dec_b1    = (const float*)d_in[24];
    const float* dec_w2    = (const float*)d_in[25];
    const float* dec_b2    = (const float*)d_in[26];
    const float* dec_w3    = (const float*)d_in[27];
    const float* dec_b3    = (const float*)d_in[28];

    float* ws   = (float*)d_ws;
    float* y    = ws + F_Y;
    float* agg  = ws + F_AGG;
    float* xd   = ws + F_XD;
    float* cls  = ws + F_CLS;
    float* dd1  = ws + F_D1;
    float* dd2  = ws + F_D2;
    float* wpad = ws + F_WPAD;
    float* dinv = ws + F_DINV;
    int* ibase  = (int*)(ws + F_IEND);
    int* indeg  = ibase;
    int* offs   = ibase + N_NODES;
    int* cursor = offs + N_NODES + 1;
    int* csr    = cursor + N_NODES;
    uintptr_t ub = ((uintptr_t)(csr + NEDGE) + 15) & ~(uintptr_t)15;
    __bf16* h1b  = (__bf16*)ub;                          // [MROWS,256] (also attention O)
    __bf16* qkvb = h1b  + (size_t)MROWS * 256;           // [MROWS,768]
    __bf16* ffbb = qkvb + (size_t)MROWS * 768;           // [MROWS,1024]
    __bf16* wt_in  = ffbb  + (size_t)MROWS * 1024;       // 2 x 768*256
    __bf16* wt_out = wt_in  + 2 * 768 * 256;             // 2 x 256*256
    __bf16* wt_f1  = wt_out + 2 * 256 * 256;             // 2 x 1024*256
    __bf16* wt_f2  = wt_f1  + 2 * 1024 * 256;            // 2 x 256*1024

    // GCN prelude
    hipMemsetAsync(indeg, 0, N_NODES * sizeof(int), stream);
    hist_kernel<<<NEDGE / 256, 256, 0, stream>>>(ei + NEDGE, indeg);
    scan_kernel<<<1, 1024, 0, stream>>>(indeg, offs, cursor, dinv);
    fill_kernel<<<NEDGE / 256, 256, 0, stream>>>(ei, cursor, csr);
    y_kernel<<<N_NODES * 64 / 256, 256, 0, stream>>>(x, p, dinv, y);
    agg_kernel<<<N_NODES / 4, 256, 0, stream>>>(y, dinv, offs, csr, agg);
    wpad_kernel<<<64, 256, 0, stream>>>(gcn_w, wpad);

    // weight transpose+cast (once per call)
    for (int l = 0; l < 2; ++l) {
        tcast_kernel<<<dim3(4, 12), 256, 0, stream>>>(in_proj_w + (size_t)l * 256 * 768,
                                                      wt_in + (size_t)l * 768 * 256, 256, 768);
        tcast_kernel<<<dim3(4, 4), 256, 0, stream>>>(out_proj_w + (size_t)l * 256 * 256,
                                                     wt_out + (size_t)l * 256 * 256, 256, 256);
        tcast_kernel<<<dim3(4, 16), 256, 0, stream>>>(ff_w1 + (size_t)l * 256 * 1024,
                                                      wt_f1 + (size_t)l * 1024 * 256, 256, 1024);
        tcast_kernel<<<dim3(16, 4), 256, 0, stream>>>(ff_w2 + (size_t)l * 1024 * 256,
                                                      wt_f2 + (size_t)l * 256 * 1024, 1024, 256);
    }

    // GCN matmul -> xd rows (remapped past cls slots), fp32
    gemm_std<0, false, true><<<dim3(256, 4), 256, 0, stream>>>(agg, 64, wpad, 256, gcn_b, xd, 256, 64);
    cls_write<<<64, 256, 0, stream>>>(cls_tok, xd);
    ln4_kernel<0><<<MROWS / 4, 256, 0, stream>>>(xd, 256, xd, ln_pre_s, ln_pre_b);

    const int MB64 = MROWS / 64;                  // 257 (exact)
    const int MG8  = (MB64 + 7) / 8;              // 33 swizzle groups
    for (int l = 0; l < 2; ++l) {
        ln4_kernel<1><<<MROWS / 4, 256, 0, stream>>>(xd, 256, h1b, norm1_s + l * WDIM, norm1_b + l * WDIM);
        gemm_v2<128, 0, 0><<<8 * 6 * MG8, 256, 0, stream>>>(
            h1b, 256, wt_in + (size_t)l * 768 * 256, in_proj_b + l * 768, qkvb, 768, 256, MB64, 6);
        attn_mfma<<<512, 256, 0, stream>>>(qkvb, h1b);
        gemm_v2<64, 0, 1><<<8 * 4 * MG8, 256, 0, stream>>>(
            h1b, 256, wt_out + (size_t)l * 256 * 256, out_proj_b + l * WDIM, xd, 256, 256, MB64, 4);
        ln4_kernel<1><<<MROWS / 4, 256, 0, stream>>>(xd, 256, h1b, norm2_s + l * WDIM, norm2_b + l * WDIM);
        gemm_v2<128, 1, 0><<<8 * 8 * MG8, 256, 0, stream>>>(
            h1b, 256, wt_f1 + (size_t)l * 1024 * 256, ff_b1 + l * DFF, ffbb, 1024, 256, MB64, 8);
        gemm_v2<64, 1, 1><<<8 * 4 * MG8, 256, 0, stream>>>(
            ffbb, 1024, wt_f2 + (size_t)l * 256 * 1024, ff_b2 + l * WDIM, xd, 256, 1024, MB64, 4);
    }

    // cls extract + ln_post + decoder
    ln4_kernel<0><<<BGRAPH / 4, 256, 0, stream>>>(xd, SEQ * WDIM, cls, ln_post_s, ln_post_b);
    dec_fc2<256, 512><<<dim3(BGRAPH, 8), 256, 0, stream>>>(cls, dec_w1, dec_b1, dd1);
    dec_fc2<512, 512><<<dim3(BGRAPH, 8), 256, 0, stream>>>(dd1, dec_w2, dec_b2, dd2);
    dec_fc2<512, 64><<<dim3(BGRAPH, 1), 256, 0, stream>>>(dd2, dec_w3, dec_b3, (float*)d_out);
}

// Round 11
// 903.541 us; speedup vs baseline: 1.0625x; 1.0625x over previous
//
#include <hip/hip_runtime.h>
#include <math.h>

// ---------------- model dims ----------------
constexpr int N_NODES = 16384;
constexpr int BGRAPH  = 64;
constexpr int NEDGE   = 524288;
constexpr int SEQ     = 257;           // NPG + cls
constexpr int WDIM    = 256;
constexpr int DFF     = 1024;
constexpr int HID     = 512;
constexpr int MROWS   = BGRAPH * SEQ;  // 16448 = 257*64 exactly

// ---------------- ws layout (float offsets for fp32 region) ----------------
constexpr size_t F_Y    = 0;                                   // [N,64]
constexpr size_t F_AGG  = F_Y    + (size_t)N_NODES * 64;       // [N,64]
constexpr size_t F_XD   = F_AGG  + (size_t)N_NODES * 64;       // [16448,256] residual (fp32)
constexpr size_t F_CLS  = F_XD   + (size_t)MROWS * WDIM;       // [64,256]
constexpr size_t F_D1   = F_CLS  + (size_t)BGRAPH * WDIM;      // [64,512]
constexpr size_t F_D2   = F_D1   + (size_t)BGRAPH * HID;       // [64,512]
constexpr size_t F_WPAD = F_D2   + (size_t)BGRAPH * HID;       // [64,256]
constexpr size_t F_DINV = F_WPAD + (size_t)64 * WDIM;          // [N]
constexpr size_t F_IEND = F_DINV + (size_t)N_NODES;

typedef __attribute__((ext_vector_type(8))) __bf16 bf16x8;
typedef __attribute__((ext_vector_type(4))) __bf16 bf16x4;
typedef __attribute__((ext_vector_type(4))) float f32x4;

__device__ __forceinline__ float gelu_f(float x) {
    float u = 0.7978845608028654f * (x + 0.044715f * x * x * x);
    return 0.5f * x * (1.0f + tanhf(u));
}

// ---------------- GCN prelude ----------------
__global__ __launch_bounds__(256) void hist_kernel(const int* __restrict__ col, int* __restrict__ indeg) {
    int e = blockIdx.x * 256 + threadIdx.x;
    atomicAdd(&indeg[col[e]], 1);
}

__global__ __launch_bounds__(1024) void scan_kernel(const int* __restrict__ indeg, int* __restrict__ offs,
                                                    int* __restrict__ cursor, float* __restrict__ dinv) {
    __shared__ int parts[1024];
    int t = threadIdx.x;
    int base = t * 16;
    int loc[16];
    int s = 0;
#pragma unroll
    for (int i = 0; i < 16; ++i) { loc[i] = indeg[base + i]; s += loc[i]; }
    parts[t] = s;
    __syncthreads();
    for (int off = 1; off < 1024; off <<= 1) {
        int v = (t >= off) ? parts[t - off] : 0;
        __syncthreads();
        parts[t] += v;
        __syncthreads();
    }
    int run = (t == 0) ? 0 : parts[t - 1];
#pragma unroll
    for (int i = 0; i < 16; ++i) {
        offs[base + i] = run;
        cursor[base + i] = run;
        dinv[base + i] = rsqrtf((float)loc[i] + 1.0f);  // deg = indeg + self-loop
        run += loc[i];
    }
    if (t == 1023) offs[N_NODES] = run;
}

__global__ __launch_bounds__(256) void fill_kernel(const int* __restrict__ ei, int* __restrict__ cursor,
                                                   int* __restrict__ csr) {
    int e = blockIdx.x * 256 + threadIdx.x;
    int r = ei[e];            // source
    int c = ei[NEDGE + e];    // destination
    int pos = atomicAdd(&cursor[c], 1);
    csr[pos] = r;
}

// xc = [x(32) | sin(p*2^j*pi)(24) | 0(8)], pre-scaled by dinv[node]
__global__ __launch_bounds__(256) void y_kernel(const float* __restrict__ x, const float* __restrict__ p,
                                                const float* __restrict__ dinv, float* __restrict__ y) {
    int idx = blockIdx.x * 256 + threadIdx.x;
    int i = idx >> 6, d = idx & 63;
    float v = 0.f;
    if (d < 32) {
        v = x[i * 32 + d];
    } else if (d < 56) {
        int dd = d - 32;
        int dim = dd >> 3, j = dd & 7;
        v = sinf(p[i * 3 + dim] * (3.14159265358979323846f * (float)(1 << j)));
    }
    y[idx] = dinv[i] * v;
}

// agg[c] = dinv[c] * (y[c] + sum_{in-edges} y[src])   (wave per node)
__global__ __launch_bounds__(256) void agg_kernel(const float* __restrict__ y, const float* __restrict__ dinv,
                                                  const int* __restrict__ offs, const int* __restrict__ csr,
                                                  float* __restrict__ agg) {
    int c = (blockIdx.x * 256 + threadIdx.x) >> 6;
    int lane = threadIdx.x & 63;
    float acc = y[(size_t)c * 64 + lane];
    int s = offs[c], e = offs[c + 1];
    for (int j = s; j < e; ++j) {
        int r = csr[j];
        acc += y[(size_t)r * 64 + lane];
    }
    agg[(size_t)c * 64 + lane] = dinv[c] * acc;
}

__global__ __launch_bounds__(256) void wpad_kernel(const float* __restrict__ w, float* __restrict__ wp) {
    int idx = blockIdx.x * 256 + threadIdx.x;
    wp[idx] = (idx < 56 * 256) ? w[idx] : 0.f;
}

__global__ __launch_bounds__(256) void cls_write(const float* __restrict__ tok, float* __restrict__ xd) {
    xd[(size_t)blockIdx.x * SEQ * WDIM + threadIdx.x] = tok[threadIdx.x];
}

// ---------------- LayerNorm: wave per row, 4 rows/block, no barriers ----------------
template <int OUTBF>
__global__ __launch_bounds__(256) void ln4_kernel(const float* __restrict__ in, int rin_stride,
                                                  void* __restrict__ out,
                                                  const float* __restrict__ g, const float* __restrict__ be) {
    int w = threadIdx.x >> 6, lane = threadIdx.x & 63;
    int row = blockIdx.x * 4 + w;
    const float* ip = in + (size_t)row * rin_stride + lane * 4;
    f32x4 v = *(const f32x4*)ip;
    float s = v[0] + v[1] + v[2] + v[3];
    float ss = v[0] * v[0] + v[1] * v[1] + v[2] * v[2] + v[3] * v[3];
#pragma unroll
    for (int off = 1; off < 64; off <<= 1) { s += __shfl_xor(s, off); ss += __shfl_xor(ss, off); }
    float mean = s * 0.00390625f;
    float var = ss * 0.00390625f - mean * mean;
    float rs = rsqrtf(var + 1e-5f);
    f32x4 gv = *(const f32x4*)(g + lane * 4);
    f32x4 bv = *(const f32x4*)(be + lane * 4);
    if (OUTBF) {
        bf16x4 o;
#pragma unroll
        for (int i = 0; i < 4; ++i) o[i] = (__bf16)((v[i] - mean) * rs * gv[i] + bv[i]);
        *(bf16x4*)((__bf16*)out + (size_t)row * 256 + lane * 4) = o;
    } else {
        f32x4 o;
#pragma unroll
        for (int i = 0; i < 4; ++i) o[i] = (v[i] - mean) * rs * gv[i] + bv[i];
        *(f32x4*)((float*)out + (size_t)row * 256 + lane * 4) = o;
    }
}

// ---------------- weight transpose+cast: W[K][N] fp32 -> Wt[N][K] bf16 ----------------
__global__ __launch_bounds__(256) void tcast_kernel(const float* __restrict__ W, __bf16* __restrict__ Wt,
                                                    int K, int N) {
    __shared__ __bf16 T[64][65];
    int t = threadIdx.x;
    int k0 = blockIdx.x << 6, n0 = blockIdx.y << 6;
#pragma unroll
    for (int i = 0; i < 16; ++i) {
        int idx = t + i * 256;
        int k = idx >> 6, n = idx & 63;
        T[k][n] = (__bf16)W[(size_t)(k0 + k) * N + n0 + n];
    }
    __syncthreads();
#pragma unroll
    for (int i = 0; i < 16; ++i) {
        int idx = t + i * 256;
        int n = idx >> 6, k = idx & 63;
        Wt[(size_t)(n0 + n) * K + k0 + k] = T[k][n];
    }
}

// ---------------- barrier-free wave-private MFMA GEMM ----------------
// One WAVE per block (64 threads). The wave owns a 64x64 C tile, staging its own
// A(64x32) and B(64x32) tiles in private LDS (pitch 36 -> conflict-free; coalesced
// 16B/lane loads). NO __syncthreads anywhere -> no vmcnt(0) barrier drain (the
// round-6..10 limiter); compiler emits only fine-grained data-dependent waits and
// prefetched loads stay in flight across sub-steps. Double-buffered LDS + static
// even/odd register sets (round-8 lesson: no dynamically-indexed reg arrays).
// Cross-block A/B re-reads are served by same-XCD L2 via the blockIdx%8 swizzle.
// OMODE 0: bf16 store. OMODE 1: fp32 store += resid. K multiple of 64; M=257*64.
constexpr int LP = 36;
template <int ACT, int OMODE>
__global__ __launch_bounds__(64) void gemm_wv(const __bf16* __restrict__ A, int lda,
                                              const __bf16* __restrict__ Bt,
                                              const float* __restrict__ bias,
                                              void* __restrict__ Cv, int ldc,
                                              int Ktot, int MBlocks, int NY) {
    __shared__ __bf16 lds[4 * 64 * LP];   // [buf0:A,B][buf1:A,B]
    __bf16* lA0 = lds;
    __bf16* lB0 = lds + 64 * LP;
    __bf16* lA1 = lds + 2 * 64 * LP;
    __bf16* lB1 = lds + 3 * 64 * LP;

    // swizzle decode: f = (m%8) + 8*(y + NY*(m/8))
    int f = blockIdx.x;
    int m8 = f & 7;
    int rest = f >> 3;
    int mg = rest / NY;
    int yb = rest - mg * NY;
    int mb = mg * 8 + m8;
    if (mb >= MBlocks) return;
    int m0 = mb << 6, n0 = yb << 6;

    int L = threadIdx.x;
    int lc = L & 15, quad = L >> 4;
    int srow = L >> 2, soff = (L & 3) << 3;   // staging: 16 rows/instr, 8-elem chunks

    const __bf16* ap = A + (size_t)(m0 + srow) * lda + soff;
    const __bf16* bp = Bt + (size_t)(n0 + srow) * Ktot + soff;
    const size_t astep = (size_t)16 * lda;
    const size_t bstep = (size_t)16 * Ktot;
    int sbase = srow * LP + soff;

    f32x4 acc[4][4] = {};

    // even (k0) / odd (k0+32) register sets — statically named (no scratch)
    bf16x8 ea0, ea1, ea2, ea3, eb0, eb1, eb2, eb3;
    bf16x8 oa0, oa1, oa2, oa3, ob0, ob1, ob2, ob3;
    ea0 = *(const bf16x8*)(ap);             ea1 = *(const bf16x8*)(ap + astep);
    ea2 = *(const bf16x8*)(ap + 2 * astep); ea3 = *(const bf16x8*)(ap + 3 * astep);
    eb0 = *(const bf16x8*)(bp);             eb1 = *(const bf16x8*)(bp + bstep);
    eb2 = *(const bf16x8*)(bp + 2 * bstep); eb3 = *(const bf16x8*)(bp + 3 * bstep);
    oa0 = *(const bf16x8*)(ap + 32);             oa1 = *(const bf16x8*)(ap + astep + 32);
    oa2 = *(const bf16x8*)(ap + 2 * astep + 32); oa3 = *(const bf16x8*)(ap + 3 * astep + 32);
    ob0 = *(const bf16x8*)(bp + 32);             ob1 = *(const bf16x8*)(bp + bstep + 32);
    ob2 = *(const bf16x8*)(bp + 2 * bstep + 32); ob3 = *(const bf16x8*)(bp + 3 * bstep + 32);

    for (int k0 = 0; k0 < Ktot; k0 += 64) {
        // ---- sub-step A: data k0 -> buf0 ----
        *(bf16x8*)(lA0 + sbase)               = ea0;
        *(bf16x8*)(lA0 + sbase + 16 * LP)     = ea1;
        *(bf16x8*)(lA0 + sbase + 32 * LP)     = ea2;
        *(bf16x8*)(lA0 + sbase + 48 * LP)     = ea3;
        *(bf16x8*)(lB0 + sbase)               = eb0;
        *(bf16x8*)(lB0 + sbase + 16 * LP)     = eb1;
        *(bf16x8*)(lB0 + sbase + 32 * LP)     = eb2;
        *(bf16x8*)(lB0 + sbase + 48 * LP)     = eb3;
        if (k0 + 64 < Ktot) {  // prefetch k0+64 (even)
            ea0 = *(const bf16x8*)(ap + k0 + 64);             ea1 = *(const bf16x8*)(ap + astep + k0 + 64);
            ea2 = *(const bf16x8*)(ap + 2 * astep + k0 + 64); ea3 = *(const bf16x8*)(ap + 3 * astep + k0 + 64);
            eb0 = *(const bf16x8*)(bp + k0 + 64);             eb1 = *(const bf16x8*)(bp + bstep + k0 + 64);
            eb2 = *(const bf16x8*)(bp + 2 * bstep + k0 + 64); eb3 = *(const bf16x8*)(bp + 3 * bstep + k0 + 64);
        }
        {
            bf16x8 af[4], bfr[4];
#pragma unroll
            for (int i = 0; i < 4; ++i) {
                af[i]  = *(const bf16x8*)(lA0 + (i * 16 + lc) * LP + quad * 8);
                bfr[i] = *(const bf16x8*)(lB0 + (i * 16 + lc) * LP + quad * 8);
            }
#pragma unroll
            for (int mt = 0; mt < 4; ++mt)
#pragma unroll
                for (int nt = 0; nt < 4; ++nt)
                    acc[mt][nt] = __builtin_amdgcn_mfma_f32_16x16x32_bf16(af[mt], bfr[nt], acc[mt][nt], 0, 0, 0);
        }
        // ---- sub-step B: data k0+32 -> buf1 ----
        *(bf16x8*)(lA1 + sbase)               = oa0;
        *(bf16x8*)(lA1 + sbase + 16 * LP)     = oa1;
        *(bf16x8*)(lA1 + sbase + 32 * LP)     = oa2;
        *(bf16x8*)(lA1 + sbase + 48 * LP)     = oa3;
        *(bf16x8*)(lB1 + sbase)               = ob0;
        *(bf16x8*)(lB1 + sbase + 16 * LP)     = ob1;
        *(bf16x8*)(lB1 + sbase + 32 * LP)     = ob2;
        *(bf16x8*)(lB1 + sbase + 48 * LP)     = ob3;
        if (k0 + 96 < Ktot) {  // prefetch k0+96 (odd)
            oa0 = *(const bf16x8*)(ap + k0 + 96);             oa1 = *(const bf16x8*)(ap + astep + k0 + 96);
            oa2 = *(const bf16x8*)(ap + 2 * astep + k0 + 96); oa3 = *(const bf16x8*)(ap + 3 * astep + k0 + 96);
            ob0 = *(const bf16x8*)(bp + k0 + 96);             ob1 = *(const bf16x8*)(bp + bstep + k0 + 96);
            ob2 = *(const bf16x8*)(bp + 2 * bstep + k0 + 96); ob3 = *(const bf16x8*)(bp + 3 * bstep + k0 + 96);
        }
        {
            bf16x8 af[4], bfr[4];
#pragma unroll
            for (int i = 0; i < 4; ++i) {
                af[i]  = *(const bf16x8*)(lA1 + (i * 16 + lc) * LP + quad * 8);
                bfr[i] = *(const bf16x8*)(lB1 + (i * 16 + lc) * LP + quad * 8);
            }
#pragma unroll
            for (int mt = 0; mt < 4; ++mt)
#pragma unroll
                for (int nt = 0; nt < 4; ++nt)
                    acc[mt][nt] = __builtin_amdgcn_mfma_f32_16x16x32_bf16(af[mt], bfr[nt], acc[mt][nt], 0, 0, 0);
        }
    }

    // epilogue (M exact multiple of 64 -> no guards)
#pragma unroll
    for (int mt = 0; mt < 4; ++mt) {
        int gmb = m0 + mt * 16 + quad * 4;
#pragma unroll
        for (int nt = 0; nt < 4; ++nt) {
            int gn = n0 + nt * 16 + lc;
            float bv = bias[gn];
#pragma unroll
            for (int r = 0; r < 4; ++r) {
                int gm = gmb + r;
                float v = acc[mt][nt][r] + bv;
                if (ACT == 1) v = gelu_f(v);
                if (OMODE == 0) {
                    ((__bf16*)Cv)[(size_t)gm * ldc + gn] = (__bf16)v;
                } else {
                    float* cp = (float*)Cv + (size_t)gm * ldc + gn;
                    *cp = v + *cp;
                }
            }
        }
    }
}

// ---------------- MFMA attention on bf16 qkv; K-fragments hoisted to registers ----------------
constexpr int PPITCH = 284;  // 568 B rows: staging stores 2-way (free), frag reads conflict-free
__global__ __launch_bounds__(256, 2) void attn_mfma(const __bf16* __restrict__ qkvb,
                                                    __bf16* __restrict__ obuf) {
    __shared__ __bf16 Vt[32][PPITCH];        // Vt[d][key], keys 257..271 zeroed
    __shared__ __bf16 Pb[4][16][PPITCH];     // per-wave unnormalized P
    int bb = blockIdx.x;
    int b = bb >> 3, h = bb & 7;
    int t = threadIdx.x;
    int w = t >> 6, L = t & 63;
    int c = L & 15, quad = L >> 4;
    const float scale = 0.17677669529663687f;  // 1/sqrt(32)
    const __bf16* qb = qkvb + (size_t)(b * SEQ) * 768 + h * 32;
    const __bf16* kb = qb + 256;
    const __bf16* vb = qb + 512;
    __bf16* ob = obuf + (size_t)(b * SEQ) * 256 + h * 32;

    // stage V^T (vector load, scalar transpose-store)
    for (int idx = t; idx < 272 * 4; idx += 256) {
        int key = idx >> 2, dc = (idx & 3) * 8;
        bf16x8 vv = {};
        if (key < SEQ) vv = *(const bf16x8*)(vb + (size_t)key * 768 + dc);
#pragma unroll
        for (int j = 0; j < 8; ++j) Vt[dc + j][key] = vv[j];
    }

    // hoist ALL K-fragments into registers once (reused across every q-tile)
    bf16x8 kfr[17];
#pragma unroll
    for (int tt = 0; tt < 17; ++tt) {
        int kr = tt * 16 + c; if (kr > 256) kr = 256;
        kfr[tt] = *(const bf16x8*)(kb + (size_t)kr * 768 + quad * 8);
    }
    __syncthreads();

#pragma unroll 1
    for (int qt = 0; qt < 5; ++qt) {
        int q0 = qt * 64 + w * 16;
        if (q0 > 256) continue;
        int ntiles = (qt == 0 && w == 0) ? 17 : (qt * 4 + w + 1);
        if (ntiles > 17) ntiles = 17;
        int nkc = (ntiles + 1) >> 1;

        // Q fragment
        bf16x8 qf;
        {
            int qr = q0 + c; if (qr > 256) qr = 256;
            qf = *(const bf16x8*)(qb + (size_t)qr * 768 + quad * 8);
        }

        // QK^T (K from registers)
        f32x4 acc[17];
#pragma unroll
        for (int tt = 0; tt < 17; ++tt) {
            if (tt >= ntiles) continue;
            f32x4 z = {0.f, 0.f, 0.f, 0.f};
            acc[tt] = __builtin_amdgcn_mfma_f32_16x16x32_bf16(qf, kfr[tt], z, 0, 0, 0);
        }

        // masked softmax in C-layout
        float inv[4];
#pragma unroll
        for (int j = 0; j < 4; ++j) {
            int q = q0 + quad * 4 + j;
            float mx = -3.0e38f;
#pragma unroll
            for (int tt = 0; tt < 17; ++tt) {
                if (tt >= ntiles) continue;
                int key = tt * 16 + c;
                bool ok = (key < SEQ) && (q == 0 || key <= q);
                float v = ok ? acc[tt][j] * scale : -3.0e38f;
                mx = fmaxf(mx, v);
            }
            mx = fmaxf(mx, __shfl_xor(mx, 1));
            mx = fmaxf(mx, __shfl_xor(mx, 2));
            mx = fmaxf(mx, __shfl_xor(mx, 4));
            mx = fmaxf(mx, __shfl_xor(mx, 8));
            float s = 0.f;
#pragma unroll
            for (int tt = 0; tt < 17; ++tt) {
                if (tt >= ntiles) continue;
                int key = tt * 16 + c;
                bool ok = (key < SEQ) && (q == 0 || key <= q);
                float pv = ok ? expf(acc[tt][j] * scale - mx) : 0.f;
                s += pv;
                Pb[w][quad * 4 + j][key] = (__bf16)pv;
            }
            if ((ntiles & 1) && ntiles < 17)
                Pb[w][quad * 4 + j][ntiles * 16 + c] = (__bf16)0.f;
            s += __shfl_xor(s, 1);
            s += __shfl_xor(s, 2);
            s += __shfl_xor(s, 4);
            s += __shfl_xor(s, 8);
            inv[j] = 1.0f / s;
        }

        // PV
        f32x4 oacc0 = {0.f, 0.f, 0.f, 0.f};
        f32x4 oacc1 = {0.f, 0.f, 0.f, 0.f};
#pragma unroll
        for (int kc = 0; kc < 9; ++kc) {
            if (kc >= nkc) continue;
            int off = kc * 32 + quad * 8;
            bf16x8 af = {};
            bf16x8 bf0 = {};
            bf16x8 bf1 = {};
            if (off < 257) {
                af  = *(const bf16x8*)&Pb[w][c][off];
                bf0 = *(const bf16x8*)&Vt[c][off];
                bf1 = *(const bf16x8*)&Vt[16 + c][off];
            }
            oacc0 = __builtin_amdgcn_mfma_f32_16x16x32_bf16(af, bf0, oacc0, 0, 0, 0);
            oacc1 = __builtin_amdgcn_mfma_f32_16x16x32_bf16(af, bf1, oacc1, 0, 0, 0);
        }

        // epilogue: apply 1/sum, write bf16 O
#pragma unroll
        for (int j = 0; j < 4; ++j) {
            int q = q0 + quad * 4 + j;
            if (q < SEQ) {
                __bf16* op = ob + (size_t)q * 256;
                op[c]      = (__bf16)(oacc0[j] * inv[j]);
                op[16 + c] = (__bf16)(oacc1[j] * inv[j]);
            }
        }
    }
}

// ---------------- fp32 tiled GEMM (kept for GCN projection) ----------------
template <int ACT, bool RESID, bool REMAP>
__global__ __launch_bounds__(256) void gemm_std(const float* __restrict__ A, int lda,
                                                const float* __restrict__ Bw, int ldb,
                                                const float* __restrict__ bias,
                                                float* __restrict__ C, int ldc, int Ktot) {
    int t = threadIdx.x;
    int m0 = blockIdx.x << 6, n0 = blockIdx.y << 6;
    __shared__ float As[16][68];
    __shared__ float Bs[16][64];
    int arow = t >> 2, akk = (t & 3) << 2;
    int bk = t >> 4, bn = (t & 15) << 2;
    int tm = (t >> 4) << 2, tn = (t & 15) << 2;
    float acc[4][4] = {};
    const float* ap = A + (size_t)(m0 + arow) * lda + akk;
    const float* bp = Bw + (size_t)bk * ldb + n0 + bn;
    for (int k0 = 0; k0 < Ktot; k0 += 16) {
        float4 av = *(const float4*)(ap + k0);
        float4 bv = *(const float4*)(bp + (size_t)k0 * ldb);
        __syncthreads();
        As[akk + 0][arow] = av.x; As[akk + 1][arow] = av.y;
        As[akk + 2][arow] = av.z; As[akk + 3][arow] = av.w;
        *(float4*)&Bs[bk][bn] = bv;
        __syncthreads();
#pragma unroll
        for (int k = 0; k < 16; ++k) {
            float4 a = *(const float4*)&As[k][tm];
            float4 b = *(const float4*)&Bs[k][tn];
            acc[0][0] += a.x * b.x; acc[0][1] += a.x * b.y; acc[0][2] += a.x * b.z; acc[0][3] += a.x * b.w;
            acc[1][0] += a.y * b.x; acc[1][1] += a.y * b.y; acc[1][2] += a.y * b.z; acc[1][3] += a.y * b.w;
            acc[2][0] += a.z * b.x; acc[2][1] += a.z * b.y; acc[2][2] += a.z * b.z; acc[2][3] += a.z * b.w;
            acc[3][0] += a.w * b.x; acc[3][1] += a.w * b.y; acc[3][2] += a.w * b.z; acc[3][3] += a.w * b.w;
        }
    }
#pragma unroll
    for (int i = 0; i < 4; ++i) {
        int gm = m0 + tm + i;
        int orow = REMAP ? (gm + (gm >> 8) + 1) : gm;  // node -> xd row (skip cls slots)
        float* cp = C + (size_t)orow * ldc + n0 + tn;
        float4 r;
        r.x = acc[i][0] + bias[n0 + tn + 0];
        r.y = acc[i][1] + bias[n0 + tn + 1];
        r.z = acc[i][2] + bias[n0 + tn + 2];
        r.w = acc[i][3] + bias[n0 + tn + 3];
        if (ACT == 1) { r.x = gelu_f(r.x); r.y = gelu_f(r.y); r.z = gelu_f(r.z); r.w = gelu_f(r.w); }
        if (ACT == 2) { r.x = fmaxf(r.x, 0.f); r.y = fmaxf(r.y, 0.f); r.z = fmaxf(r.z, 0.f); r.w = fmaxf(r.w, 0.f); }
        if (RESID) {
            float4 o = *(const float4*)cp;
            r.x += o.x; r.y += o.y; r.z += o.z; r.w += o.w;
        }
        *(float4*)cp = r;
    }
}

// ---------------- decoder FC: grid (sample, out-chunk), 4 waves split K ----------------
template <int K, int NOUT>
__global__ __launch_bounds__(256) void dec_fc2(const float* __restrict__ in, const float* __restrict__ w,
                                               const float* __restrict__ bia, float* __restrict__ out) {
    __shared__ float rowbuf[K];
    __shared__ float part[4][64];
    int b = blockIdx.x, c = blockIdx.y, t = threadIdx.x;
    for (int i = t; i < K; i += 256) rowbuf[i] = in[(size_t)b * K + i];
    __syncthreads();
    int lane = t & 63, wv = t >> 6;
    int n = c * 64 + lane;
    const int KQ = K / 4;
    const float* wp = w + (size_t)(wv * KQ) * NOUT + n;
    float s = 0.f;
#pragma unroll 8
    for (int k = 0; k < KQ; ++k) s += rowbuf[wv * KQ + k] * wp[(size_t)k * NOUT];
    part[wv][lane] = s;
    __syncthreads();
    if (wv == 0) {
        float r = part[0][lane] + part[1][lane] + part[2][lane] + part[3][lane] + bia[n];
        out[(size_t)b * NOUT + n] = fmaxf(r, 0.f);
    }
}

// ---------------- launch ----------------
extern "C" void kernel_launch(void* const* d_in, const int* in_sizes, int n_in,
                              void* d_out, int out_size, void* d_ws, size_t ws_size,
                              hipStream_t stream) {
    const float* x         = (const float*)d_in[0];
    const float* p         = (const float*)d_in[1];
    const int*   ei        = (const int*)d_in[2];
    const float* gcn_w     = (const float*)d_in[4];
    const float* gcn_b     = (const float*)d_in[5];
    const float* cls_tok   = (const float*)d_in[6];
    const float* ln_pre_s  = (const float*)d_in[7];
    const float* ln_pre_b  = (const float*)d_in[8];
    const float* norm1_s   = (const float*)d_in[9];
    const float* norm1_b   = (const float*)d_in[10];
    const float* in_proj_w = (const float*)d_in[11];
    const float* in_proj_b = (const float*)d_in[12];
    const float* out_proj_w= (const float*)d_in[13];
    const float* out_proj_b= (const float*)d_in[14];
    const float* norm2_s   = (const float*)d_in[15];
    const float* norm2_b   = (const float*)d_in[16];
    const float* ff_w1     = (const float*)d_in[17];
    const float* ff_b1     = (const float*)d_in[18];
    const float* ff_w2     = (const float*)d_in[19];
    const float* ff_b2     = (const float*)d_in[20];
    const float* ln_post_s = (const float*)d_in[21];
    const float* ln_post_b = (const float*)d_in[22];
    const float* dec_w1    = (const float*)d_in[23];
    const float* dec_b1    = (const float*)d_in[24];
    const float* dec_w2    = (const float*)d_in[25];
    const float* dec_b2    = (const float*)d_in[26];
    const float* dec_w3    = (const float*)d_in[27];
    const float* dec_b3    = (const float*)d_in[28];

    float* ws   = (float*)d_ws;
    float* y    = ws + F_Y;
    float* agg  = ws + F_AGG;
    float* xd   = ws + F_XD;
    float* cls  = ws + F_CLS;
    float* dd1  = ws + F_D1;
    float* dd2  = ws + F_D2;
    float* wpad = ws + F_WPAD;
    float* dinv = ws + F_DINV;
    int* ibase  = (int*)(ws + F_IEND);
    int* indeg  = ibase;
    int* offs   = ibase + N_NODES;
    int* cursor = offs + N_NODES + 1;
    int* csr    = cursor + N_NODES;
    uintptr_t ub = ((uintptr_t)(csr + NEDGE) + 15) & ~(uintptr_t)15;
    __bf16* h1b  = (__bf16*)ub;                          // [MROWS,256] (also attention O)
    __bf16* qkvb = h1b  + (size_t)MROWS * 256;           // [MROWS,768]
    __bf16* ffbb = qkvb + (size_t)MROWS * 768;           // [MROWS,1024]
    __bf16* wt_in  = ffbb  + (size_t)MROWS * 1024;       // 2 x 768*256
    __bf16* wt_out = wt_in  + 2 * 768 * 256;             // 2 x 256*256
    __bf16* wt_f1  = wt_out + 2 * 256 * 256;             // 2 x 1024*256
    __bf16* wt_f2  = wt_f1  + 2 * 1024 * 256;            // 2 x 256*1024

    // GCN prelude
    hipMemsetAsync(indeg, 0, N_NODES * sizeof(int), stream);
    hist_kernel<<<NEDGE / 256, 256, 0, stream>>>(ei + NEDGE, indeg);
    scan_kernel<<<1, 1024, 0, stream>>>(indeg, offs, cursor, dinv);
    fill_kernel<<<NEDGE / 256, 256, 0, stream>>>(ei, cursor, csr);
    y_kernel<<<N_NODES * 64 / 256, 256, 0, stream>>>(x, p, dinv, y);
    agg_kernel<<<N_NODES / 4, 256, 0, stream>>>(y, dinv, offs, csr, agg);
    wpad_kernel<<<64, 256, 0, stream>>>(gcn_w, wpad);

    // weight transpose+cast (once per call)
    for (int l = 0; l < 2; ++l) {
        tcast_kernel<<<dim3(4, 12), 256, 0, stream>>>(in_proj_w + (size_t)l * 256 * 768,
                                                      wt_in + (size_t)l * 768 * 256, 256, 768);
        tcast_kernel<<<dim3(4, 4), 256, 0, stream>>>(out_proj_w + (size_t)l * 256 * 256,
                                                     wt_out + (size_t)l * 256 * 256, 256, 256);
        tcast_kernel<<<dim3(4, 16), 256, 0, stream>>>(ff_w1 + (size_t)l * 256 * 1024,
                                                      wt_f1 + (size_t)l * 1024 * 256, 256, 1024);
        tcast_kernel<<<dim3(16, 4), 256, 0, stream>>>(ff_w2 + (size_t)l * 1024 * 256,
                                                      wt_f2 + (size_t)l * 256 * 1024, 1024, 256);
    }

    // GCN matmul -> xd rows (remapped past cls slots), fp32
    gemm_std<0, false, true><<<dim3(256, 4), 256, 0, stream>>>(agg, 64, wpad, 256, gcn_b, xd, 256, 64);
    cls_write<<<64, 256, 0, stream>>>(cls_tok, xd);
    ln4_kernel<0><<<MROWS / 4, 256, 0, stream>>>(xd, 256, xd, ln_pre_s, ln_pre_b);

    const int MB64 = MROWS / 64;                  // 257 (exact)
    const int MG8  = (MB64 + 7) / 8;              // 33 swizzle groups
    for (int l = 0; l < 2; ++l) {
        ln4_kernel<1><<<MROWS / 4, 256, 0, stream>>>(xd, 256, h1b, norm1_s + l * WDIM, norm1_b + l * WDIM);
        gemm_wv<0, 0><<<8 * 12 * MG8, 64, 0, stream>>>(
            h1b, 256, wt_in + (size_t)l * 768 * 256, in_proj_b + l * 768, qkvb, 768, 256, MB64, 12);
        attn_mfma<<<512, 256, 0, stream>>>(qkvb, h1b);
        gemm_wv<0, 1><<<8 * 4 * MG8, 64, 0, stream>>>(
            h1b, 256, wt_out + (size_t)l * 256 * 256, out_proj_b + l * WDIM, xd, 256, 256, MB64, 4);
        ln4_kernel<1><<<MROWS / 4, 256, 0, stream>>>(xd, 256, h1b, norm2_s + l * WDIM, norm2_b + l * WDIM);
        gemm_wv<1, 0><<<8 * 16 * MG8, 64, 0, stream>>>(
            h1b, 256, wt_f1 + (size_t)l * 1024 * 256, ff_b1 + l * DFF, ffbb, 1024, 256, MB64, 16);
        gemm_wv<1, 1><<<8 * 4 * MG8, 64, 0, stream>>>(
            ffbb, 1024, wt_f2 + (size_t)l * 256 * 1024, ff_b2 + l * WDIM, xd, 256, 1024, MB64, 4);
    }

    // cls extract + ln_post + decoder
    ln4_kernel<0><<<BGRAPH / 4, 256, 0, stream>>>(xd, SEQ * WDIM, cls, ln_post_s, ln_post_b);
    dec_fc2<256, 512><<<dim3(BGRAPH, 8), 256, 0, stream>>>(cls, dec_w1, dec_b1, dd1);
    dec_fc2<512, 512><<<dim3(BGRAPH, 8), 256, 0, stream>>>(dd1, dec_w2, dec_b2, dd2);
    dec_fc2<512, 64><<<dim3(BGRAPH, 1), 256, 0, stream>>>(dd2, dec_w3, dec_b3, (float*)d_out);
}

// Round 12
// 714.413 us; speedup vs baseline: 1.3438x; 1.2647x over previous
//
#include <hip/hip_runtime.h>
#include <math.h>

// ---------------- model dims ----------------
constexpr int N_NODES = 16384;
constexpr int BGRAPH  = 64;
constexpr int NEDGE   = 524288;
constexpr int SEQ     = 257;           // NPG + cls
constexpr int WDIM    = 256;
constexpr int DFF     = 1024;
constexpr int HID     = 512;
constexpr int MROWS   = BGRAPH * SEQ;  // 16448

// ---------------- ws layout (float offsets for fp32 region) ----------------
constexpr size_t F_Y    = 0;                                   // [N,64]
constexpr size_t F_AGG  = F_Y    + (size_t)N_NODES * 64;       // [N,64]
constexpr size_t F_XD   = F_AGG  + (size_t)N_NODES * 64;       // [16448,256] residual (fp32)
constexpr size_t F_CLS  = F_XD   + (size_t)MROWS * WDIM;       // [64,256]
constexpr size_t F_D1   = F_CLS  + (size_t)BGRAPH * WDIM;      // [64,512]
constexpr size_t F_D2   = F_D1   + (size_t)BGRAPH * HID;       // [64,512]
constexpr size_t F_WPAD = F_D2   + (size_t)BGRAPH * HID;       // [64,256]
constexpr size_t F_DINV = F_WPAD + (size_t)64 * WDIM;          // [N]
constexpr size_t F_IEND = F_DINV + (size_t)N_NODES;

typedef __attribute__((ext_vector_type(8))) __bf16 bf16x8;
typedef __attribute__((ext_vector_type(4))) __bf16 bf16x4;
typedef __attribute__((ext_vector_type(4))) float f32x4;

__device__ __forceinline__ float gelu_f(float x) {
    float u = 0.7978845608028654f * (x + 0.044715f * x * x * x);
    return 0.5f * x * (1.0f + tanhf(u));
}

// ---------------- GCN prelude ----------------
__global__ __launch_bounds__(256) void hist_kernel(const int* __restrict__ col, int* __restrict__ indeg) {
    int e = blockIdx.x * 256 + threadIdx.x;
    atomicAdd(&indeg[col[e]], 1);
}

__global__ __launch_bounds__(1024) void scan_kernel(const int* __restrict__ indeg, int* __restrict__ offs,
                                                    int* __restrict__ cursor, float* __restrict__ dinv) {
    __shared__ int parts[1024];
    int t = threadIdx.x;
    int base = t * 16;
    int loc[16];
    int s = 0;
#pragma unroll
    for (int i = 0; i < 16; ++i) { loc[i] = indeg[base + i]; s += loc[i]; }
    parts[t] = s;
    __syncthreads();
    for (int off = 1; off < 1024; off <<= 1) {
        int v = (t >= off) ? parts[t - off] : 0;
        __syncthreads();
        parts[t] += v;
        __syncthreads();
    }
    int run = (t == 0) ? 0 : parts[t - 1];
#pragma unroll
    for (int i = 0; i < 16; ++i) {
        offs[base + i] = run;
        cursor[base + i] = run;
        dinv[base + i] = rsqrtf((float)loc[i] + 1.0f);  // deg = indeg + self-loop
        run += loc[i];
    }
    if (t == 1023) offs[N_NODES] = run;
}

__global__ __launch_bounds__(256) void fill_kernel(const int* __restrict__ ei, int* __restrict__ cursor,
                                                   int* __restrict__ csr) {
    int e = blockIdx.x * 256 + threadIdx.x;
    int r = ei[e];            // source
    int c = ei[NEDGE + e];    // destination
    int pos = atomicAdd(&cursor[c], 1);
    csr[pos] = r;
}

// xc = [x(32) | sin(p*2^j*pi)(24) | 0(8)], pre-scaled by dinv[node]
__global__ __launch_bounds__(256) void y_kernel(const float* __restrict__ x, const float* __restrict__ p,
                                                const float* __restrict__ dinv, float* __restrict__ y) {
    int idx = blockIdx.x * 256 + threadIdx.x;
    int i = idx >> 6, d = idx & 63;
    float v = 0.f;
    if (d < 32) {
        v = x[i * 32 + d];
    } else if (d < 56) {
        int dd = d - 32;
        int dim = dd >> 3, j = dd & 7;
        v = sinf(p[i * 3 + dim] * (3.14159265358979323846f * (float)(1 << j)));
    }
    y[idx] = dinv[i] * v;
}

// agg[c] = dinv[c] * (y[c] + sum_{in-edges} y[src])   (wave per node)
__global__ __launch_bounds__(256) void agg_kernel(const float* __restrict__ y, const float* __restrict__ dinv,
                                                  const int* __restrict__ offs, const int* __restrict__ csr,
                                                  float* __restrict__ agg) {
    int c = (blockIdx.x * 256 + threadIdx.x) >> 6;
    int lane = threadIdx.x & 63;
    float acc = y[(size_t)c * 64 + lane];
    int s = offs[c], e = offs[c + 1];
    for (int j = s; j < e; ++j) {
        int r = csr[j];
        acc += y[(size_t)r * 64 + lane];
    }
    agg[(size_t)c * 64 + lane] = dinv[c] * acc;
}

__global__ __launch_bounds__(256) void wpad_kernel(const float* __restrict__ w, float* __restrict__ wp) {
    int idx = blockIdx.x * 256 + threadIdx.x;
    wp[idx] = (idx < 56 * 256) ? w[idx] : 0.f;
}

__global__ __launch_bounds__(256) void cls_write(const float* __restrict__ tok, float* __restrict__ xd) {
    xd[(size_t)blockIdx.x * SEQ * WDIM + threadIdx.x] = tok[threadIdx.x];
}

// ---------------- LayerNorm: wave per row, 4 rows/block, no barriers ----------------
template <int OUTBF>
__global__ __launch_bounds__(256) void ln4_kernel(const float* __restrict__ in, int rin_stride,
                                                  void* __restrict__ out,
                                                  const float* __restrict__ g, const float* __restrict__ be) {
    int w = threadIdx.x >> 6, lane = threadIdx.x & 63;
    int row = blockIdx.x * 4 + w;
    const float* ip = in + (size_t)row * rin_stride + lane * 4;
    f32x4 v = *(const f32x4*)ip;
    float s = v[0] + v[1] + v[2] + v[3];
    float ss = v[0] * v[0] + v[1] * v[1] + v[2] * v[2] + v[3] * v[3];
#pragma unroll
    for (int off = 1; off < 64; off <<= 1) { s += __shfl_xor(s, off); ss += __shfl_xor(ss, off); }
    float mean = s * 0.00390625f;
    float var = ss * 0.00390625f - mean * mean;
    float rs = rsqrtf(var + 1e-5f);
    f32x4 gv = *(const f32x4*)(g + lane * 4);
    f32x4 bv = *(const f32x4*)(be + lane * 4);
    if (OUTBF) {
        bf16x4 o;
#pragma unroll
        for (int i = 0; i < 4; ++i) o[i] = (__bf16)((v[i] - mean) * rs * gv[i] + bv[i]);
        *(bf16x4*)((__bf16*)out + (size_t)row * 256 + lane * 4) = o;
    } else {
        f32x4 o;
#pragma unroll
        for (int i = 0; i < 4; ++i) o[i] = (v[i] - mean) * rs * gv[i] + bv[i];
        *(f32x4*)((float*)out + (size_t)row * 256 + lane * 4) = o;
    }
}

// ---------------- weight transpose+cast: W[K][N] fp32 -> Wt[N][K] bf16 ----------------
__global__ __launch_bounds__(256) void tcast_kernel(const float* __restrict__ W, __bf16* __restrict__ Wt,
                                                    int K, int N) {
    __shared__ __bf16 T[64][65];
    int t = threadIdx.x;
    int k0 = blockIdx.x << 6, n0 = blockIdx.y << 6;
#pragma unroll
    for (int i = 0; i < 16; ++i) {
        int idx = t + i * 256;
        int k = idx >> 6, n = idx & 63;
        T[k][n] = (__bf16)W[(size_t)(k0 + k) * N + n0 + n];
    }
    __syncthreads();
#pragma unroll
    for (int i = 0; i < 16; ++i) {
        int idx = t + i * 256;
        int n = idx >> 6, k = idx & 63;
        Wt[(size_t)(n0 + n) * K + k0 + k] = T[k][n];
    }
}

// ---------------- bf16 MFMA GEMM: BM=128, BN in {128,64}, BK=64 per barrier-pair ----------------
// Round-9 structure (coalesced staging, LDS pitch 36, static even/odd prefetch
// registers) with BOTH 32-K halves published per barrier pair: HALF the barrier
// count of round 9 for identical MFMA order (bit-identical numerics). Prefetch
// distance stays 1 full iteration (64 K). No dynamically-indexed register
// arrays (round-8 scratch lesson). 1D grid with XCD swizzle.
// OMODE 0: bf16 store. OMODE 1: fp32 store += resid. K must be a multiple of 64.
constexpr int LP = 36;
template <int BN, int ACT, int OMODE>
__global__ __launch_bounds__(256) void gemm_bf(const __bf16* __restrict__ A, int lda,
                                               const __bf16* __restrict__ Bt,
                                               const float* __restrict__ bias,
                                               void* __restrict__ Cv, int ldc,
                                               int Ktot, int Mrows, int MBlocks, int NY) {
    constexpr int NTW = BN / 32;       // n-tiles per wave
    constexpr int AH = 128 * LP;       // A half-buffer stride (elements)
    constexpr int BH = BN * LP;        // B half-buffer stride
    __shared__ __bf16 As[2 * 128 * LP];
    __shared__ __bf16 Bs[2 * BN * LP];
    // swizzle decode: f = (m%8) + 8*(y + NY*(m/8))
    int f = blockIdx.x;
    int m8 = f & 7;
    int rest = f >> 3;
    int mg = rest / NY;
    int yb = rest - mg * NY;
    int mb = mg * 8 + m8;
    if (mb >= MBlocks) return;
    int m0 = mb << 7, n0 = yb * BN;

    int t = threadIdx.x;
    int w = t >> 6, L = t & 63;
    int wm = w >> 1, wn = w & 1;
    int lc = L & 15, quad = L >> 4;

    // A staging: thread t -> row t>>1, 16-elem chunk (t&1)*16 (two bf16x8)
    int sa_row = t >> 1, sa_off = (t & 1) << 4;
    const __bf16* ap = A + (size_t)(m0 + sa_row) * lda + sa_off;
    __bf16* as_dst = &As[sa_row * LP + sa_off];
    const __bf16* bp;
    __bf16* bs_dst;
    if constexpr (BN == 128) {
        bp = Bt + (size_t)(n0 + sa_row) * Ktot + sa_off;
        bs_dst = &Bs[sa_row * LP + sa_off];
    } else {
        int sb_row = t >> 2, sb_off = (t & 3) << 3;
        bp = Bt + (size_t)(n0 + sb_row) * Ktot + sb_off;
        bs_dst = &Bs[sb_row * LP + sb_off];
    }

    int a_base = (wm * 64 + lc) * LP + quad * 8;
    int b_base = (wn * (BN / 2) + lc) * LP + quad * 8;

    f32x4 acc[4][NTW] = {};

    // even (k0) and odd (k0+32) tile register sets — statically named
    bf16x8 ea0, ea1, eb0, eb1, oa0, oa1, ob0, ob1;
    ea0 = *(const bf16x8*)(ap);        ea1 = *(const bf16x8*)(ap + 8);
    oa0 = *(const bf16x8*)(ap + 32);   oa1 = *(const bf16x8*)(ap + 40);
    if constexpr (BN == 128) {
        eb0 = *(const bf16x8*)(bp);        eb1 = *(const bf16x8*)(bp + 8);
        ob0 = *(const bf16x8*)(bp + 32);   ob1 = *(const bf16x8*)(bp + 40);
    } else {
        eb0 = *(const bf16x8*)(bp);
        ob0 = *(const bf16x8*)(bp + 32);
    }

    for (int k0 = 0; k0 < Ktot; k0 += 64) {
        __syncthreads();
        // publish both halves: k0 -> buffer 0, k0+32 -> buffer 1
        *(bf16x8*)as_dst = ea0;
        *(bf16x8*)(as_dst + 8) = ea1;
        *(bf16x8*)(as_dst + AH) = oa0;
        *(bf16x8*)(as_dst + AH + 8) = oa1;
        if constexpr (BN == 128) {
            *(bf16x8*)bs_dst = eb0;
            *(bf16x8*)(bs_dst + 8) = eb1;
            *(bf16x8*)(bs_dst + BH) = ob0;
            *(bf16x8*)(bs_dst + BH + 8) = ob1;
        } else {
            *(bf16x8*)bs_dst = eb0;
            *(bf16x8*)(bs_dst + BH) = ob0;
        }
        __syncthreads();
        if (k0 + 64 < Ktot) {     // prefetch next iteration's two halves
            ea0 = *(const bf16x8*)(ap + k0 + 64);
            ea1 = *(const bf16x8*)(ap + k0 + 72);
            oa0 = *(const bf16x8*)(ap + k0 + 96);
            oa1 = *(const bf16x8*)(ap + k0 + 104);
            if constexpr (BN == 128) {
                eb0 = *(const bf16x8*)(bp + k0 + 64);
                eb1 = *(const bf16x8*)(bp + k0 + 72);
                ob0 = *(const bf16x8*)(bp + k0 + 96);
                ob1 = *(const bf16x8*)(bp + k0 + 104);
            } else {
                eb0 = *(const bf16x8*)(bp + k0 + 64);
                ob0 = *(const bf16x8*)(bp + k0 + 96);
            }
        }
        // half 0 (k0): same MFMA order as round 9
        {
            bf16x8 af[4], bfr[NTW];
#pragma unroll
            for (int i = 0; i < 4; ++i) af[i] = *(const bf16x8*)&As[a_base + i * 16 * LP];
#pragma unroll
            for (int i = 0; i < NTW; ++i) bfr[i] = *(const bf16x8*)&Bs[b_base + i * 16 * LP];
#pragma unroll
            for (int mt = 0; mt < 4; ++mt)
#pragma unroll
                for (int nt = 0; nt < NTW; ++nt)
                    acc[mt][nt] = __builtin_amdgcn_mfma_f32_16x16x32_bf16(af[mt], bfr[nt], acc[mt][nt], 0, 0, 0);
        }
        // half 1 (k0+32)
        {
            bf16x8 af[4], bfr[NTW];
#pragma unroll
            for (int i = 0; i < 4; ++i) af[i] = *(const bf16x8*)&As[AH + a_base + i * 16 * LP];
#pragma unroll
            for (int i = 0; i < NTW; ++i) bfr[i] = *(const bf16x8*)&Bs[BH + b_base + i * 16 * LP];
#pragma unroll
            for (int mt = 0; mt < 4; ++mt)
#pragma unroll
                for (int nt = 0; nt < NTW; ++nt)
                    acc[mt][nt] = __builtin_amdgcn_mfma_f32_16x16x32_bf16(af[mt], bfr[nt], acc[mt][nt], 0, 0, 0);
        }
    }

#pragma unroll
    for (int mt = 0; mt < 4; ++mt) {
        int gmb = m0 + wm * 64 + mt * 16 + quad * 4;
#pragma unroll
        for (int nt = 0; nt < NTW; ++nt) {
            int gn = n0 + wn * (BN / 2) + nt * 16 + lc;
            float bv = bias[gn];
#pragma unroll
            for (int r = 0; r < 4; ++r) {
                int gm = gmb + r;
                if (gm >= Mrows) continue;
                float v = acc[mt][nt][r] + bv;
                if (ACT == 1) v = gelu_f(v);
                if (OMODE == 0) {
                    ((__bf16*)Cv)[(size_t)gm * ldc + gn] = (__bf16)v;
                } else {
                    float* cp = (float*)Cv + (size_t)gm * ldc + gn;
                    *cp = v + *cp;
                }
            }
        }
    }
}

// ---------------- MFMA attention on bf16 qkv; K-fragments hoisted to registers ----------------
constexpr int PPITCH = 284;  // 568 B rows: staging stores 2-way (free), frag reads conflict-free
__global__ __launch_bounds__(256, 2) void attn_mfma(const __bf16* __restrict__ qkvb,
                                                    __bf16* __restrict__ obuf) {
    __shared__ __bf16 Vt[32][PPITCH];        // Vt[d][key], keys 257..271 zeroed
    __shared__ __bf16 Pb[4][16][PPITCH];     // per-wave unnormalized P
    int bb = blockIdx.x;
    int b = bb >> 3, h = bb & 7;
    int t = threadIdx.x;
    int w = t >> 6, L = t & 63;
    int c = L & 15, quad = L >> 4;
    const float scale = 0.17677669529663687f;  // 1/sqrt(32)
    const __bf16* qb = qkvb + (size_t)(b * SEQ) * 768 + h * 32;
    const __bf16* kb = qb + 256;
    const __bf16* vb = qb + 512;
    __bf16* ob = obuf + (size_t)(b * SEQ) * 256 + h * 32;

    // stage V^T (vector load, scalar transpose-store)
    for (int idx = t; idx < 272 * 4; idx += 256) {
        int key = idx >> 2, dc = (idx & 3) * 8;
        bf16x8 vv = {};
        if (key < SEQ) vv = *(const bf16x8*)(vb + (size_t)key * 768 + dc);
#pragma unroll
        for (int j = 0; j < 8; ++j) Vt[dc + j][key] = vv[j];
    }

    // hoist ALL K-fragments into registers once (reused across every q-tile)
    bf16x8 kfr[17];
#pragma unroll
    for (int tt = 0; tt < 17; ++tt) {
        int kr = tt * 16 + c; if (kr > 256) kr = 256;
        kfr[tt] = *(const bf16x8*)(kb + (size_t)kr * 768 + quad * 8);
    }
    __syncthreads();

#pragma unroll 1
    for (int qt = 0; qt < 5; ++qt) {
        int q0 = qt * 64 + w * 16;
        if (q0 > 256) continue;
        int ntiles = (qt == 0 && w == 0) ? 17 : (qt * 4 + w + 1);
        if (ntiles > 17) ntiles = 17;
        int nkc = (ntiles + 1) >> 1;

        // Q fragment
        bf16x8 qf;
        {
            int qr = q0 + c; if (qr > 256) qr = 256;
            qf = *(const bf16x8*)(qb + (size_t)qr * 768 + quad * 8);
        }

        // QK^T (K from registers)
        f32x4 acc[17];
#pragma unroll
        for (int tt = 0; tt < 17; ++tt) {
            if (tt >= ntiles) continue;
            f32x4 z = {0.f, 0.f, 0.f, 0.f};
            acc[tt] = __builtin_amdgcn_mfma_f32_16x16x32_bf16(qf, kfr[tt], z, 0, 0, 0);
        }

        // masked softmax in C-layout
        float inv[4];
#pragma unroll
        for (int j = 0; j < 4; ++j) {
            int q = q0 + quad * 4 + j;
            float mx = -3.0e38f;
#pragma unroll
            for (int tt = 0; tt < 17; ++tt) {
                if (tt >= ntiles) continue;
                int key = tt * 16 + c;
                bool ok = (key < SEQ) && (q == 0 || key <= q);
                float v = ok ? acc[tt][j] * scale : -3.0e38f;
                mx = fmaxf(mx, v);
            }
            mx = fmaxf(mx, __shfl_xor(mx, 1));
            mx = fmaxf(mx, __shfl_xor(mx, 2));
            mx = fmaxf(mx, __shfl_xor(mx, 4));
            mx = fmaxf(mx, __shfl_xor(mx, 8));
            float s = 0.f;
#pragma unroll
            for (int tt = 0; tt < 17; ++tt) {
                if (tt >= ntiles) continue;
                int key = tt * 16 + c;
                bool ok = (key < SEQ) && (q == 0 || key <= q);
                float pv = ok ? expf(acc[tt][j] * scale - mx) : 0.f;
                s += pv;
                Pb[w][quad * 4 + j][key] = (__bf16)pv;
            }
            if ((ntiles & 1) && ntiles < 17)
                Pb[w][quad * 4 + j][ntiles * 16 + c] = (__bf16)0.f;
            s += __shfl_xor(s, 1);
            s += __shfl_xor(s, 2);
            s += __shfl_xor(s, 4);
            s += __shfl_xor(s, 8);
            inv[j] = 1.0f / s;
        }

        // PV
        f32x4 oacc0 = {0.f, 0.f, 0.f, 0.f};
        f32x4 oacc1 = {0.f, 0.f, 0.f, 0.f};
#pragma unroll
        for (int kc = 0; kc < 9; ++kc) {
            if (kc >= nkc) continue;
            int off = kc * 32 + quad * 8;
            bf16x8 af = {};
            bf16x8 bf0 = {};
            bf16x8 bf1 = {};
            if (off < 257) {
                af  = *(const bf16x8*)&Pb[w][c][off];
                bf0 = *(const bf16x8*)&Vt[c][off];
                bf1 = *(const bf16x8*)&Vt[16 + c][off];
            }
            oacc0 = __builtin_amdgcn_mfma_f32_16x16x32_bf16(af, bf0, oacc0, 0, 0, 0);
            oacc1 = __builtin_amdgcn_mfma_f32_16x16x32_bf16(af, bf1, oacc1, 0, 0, 0);
        }

        // epilogue: apply 1/sum, write bf16 O
#pragma unroll
        for (int j = 0; j < 4; ++j) {
            int q = q0 + quad * 4 + j;
            if (q < SEQ) {
                __bf16* op = ob + (size_t)q * 256;
                op[c]      = (__bf16)(oacc0[j] * inv[j]);
                op[16 + c] = (__bf16)(oacc1[j] * inv[j]);
            }
        }
    }
}

// ---------------- fp32 tiled GEMM (kept for GCN projection) ----------------
template <int ACT, bool RESID, bool REMAP>
__global__ __launch_bounds__(256) void gemm_std(const float* __restrict__ A, int lda,
                                                const float* __restrict__ Bw, int ldb,
                                                const float* __restrict__ bias,
                                                float* __restrict__ C, int ldc, int Ktot) {
    int t = threadIdx.x;
    int m0 = blockIdx.x << 6, n0 = blockIdx.y << 6;
    __shared__ float As[16][68];
    __shared__ float Bs[16][64];
    int arow = t >> 2, akk = (t & 3) << 2;
    int bk = t >> 4, bn = (t & 15) << 2;
    int tm = (t >> 4) << 2, tn = (t & 15) << 2;
    float acc[4][4] = {};
    const float* ap = A + (size_t)(m0 + arow) * lda + akk;
    const float* bp = Bw + (size_t)bk * ldb + n0 + bn;
    for (int k0 = 0; k0 < Ktot; k0 += 16) {
        float4 av = *(const float4*)(ap + k0);
        float4 bv = *(const float4*)(bp + (size_t)k0 * ldb);
        __syncthreads();
        As[akk + 0][arow] = av.x; As[akk + 1][arow] = av.y;
        As[akk + 2][arow] = av.z; As[akk + 3][arow] = av.w;
        *(float4*)&Bs[bk][bn] = bv;
        __syncthreads();
#pragma unroll
        for (int k = 0; k < 16; ++k) {
            float4 a = *(const float4*)&As[k][tm];
            float4 b = *(const float4*)&Bs[k][tn];
            acc[0][0] += a.x * b.x; acc[0][1] += a.x * b.y; acc[0][2] += a.x * b.z; acc[0][3] += a.x * b.w;
            acc[1][0] += a.y * b.x; acc[1][1] += a.y * b.y; acc[1][2] += a.y * b.z; acc[1][3] += a.y * b.w;
            acc[2][0] += a.z * b.x; acc[2][1] += a.z * b.y; acc[2][2] += a.z * b.z; acc[2][3] += a.z * b.w;
            acc[3][0] += a.w * b.x; acc[3][1] += a.w * b.y; acc[3][2] += a.w * b.z; acc[3][3] += a.w * b.w;
        }
    }
#pragma unroll
    for (int i = 0; i < 4; ++i) {
        int gm = m0 + tm + i;
        int orow = REMAP ? (gm + (gm >> 8) + 1) : gm;  // node -> xd row (skip cls slots)
        float* cp = C + (size_t)orow * ldc + n0 + tn;
        float4 r;
        r.x = acc[i][0] + bias[n0 + tn + 0];
        r.y = acc[i][1] + bias[n0 + tn + 1];
        r.z = acc[i][2] + bias[n0 + tn + 2];
        r.w = acc[i][3] + bias[n0 + tn + 3];
        if (ACT == 1) { r.x = gelu_f(r.x); r.y = gelu_f(r.y); r.z = gelu_f(r.z); r.w = gelu_f(r.w); }
        if (ACT == 2) { r.x = fmaxf(r.x, 0.f); r.y = fmaxf(r.y, 0.f); r.z = fmaxf(r.z, 0.f); r.w = fmaxf(r.w, 0.f); }
        if (RESID) {
            float4 o = *(const float4*)cp;
            r.x += o.x; r.y += o.y; r.z += o.z; r.w += o.w;
        }
        *(float4*)cp = r;
    }
}

// ---------------- decoder FC: grid (sample, out-chunk), 4 waves split K ----------------
template <int K, int NOUT>
__global__ __launch_bounds__(256) void dec_fc2(const float* __restrict__ in, const float* __restrict__ w,
                                               const float* __restrict__ bia, float* __restrict__ out) {
    __shared__ float rowbuf[K];
    __shared__ float part[4][64];
    int b = blockIdx.x, c = blockIdx.y, t = threadIdx.x;
    for (int i = t; i < K; i += 256) rowbuf[i] = in[(size_t)b * K + i];
    __syncthreads();
    int lane = t & 63, wv = t >> 6;
    int n = c * 64 + lane;
    const int KQ = K / 4;
    const float* wp = w + (size_t)(wv * KQ) * NOUT + n;
    float s = 0.f;
#pragma unroll 8
    for (int k = 0; k < KQ; ++k) s += rowbuf[wv * KQ + k] * wp[(size_t)k * NOUT];
    part[wv][lane] = s;
    __syncthreads();
    if (wv == 0) {
        float r = part[0][lane] + part[1][lane] + part[2][lane] + part[3][lane] + bia[n];
        out[(size_t)b * NOUT + n] = fmaxf(r, 0.f);
    }
}

// ---------------- launch ----------------
extern "C" void kernel_launch(void* const* d_in, const int* in_sizes, int n_in,
                              void* d_out, int out_size, void* d_ws, size_t ws_size,
                              hipStream_t stream) {
    const float* x         = (const float*)d_in[0];
    const float* p         = (const float*)d_in[1];
    const int*   ei        = (const int*)d_in[2];
    const float* gcn_w     = (const float*)d_in[4];
    const float* gcn_b     = (const float*)d_in[5];
    const float* cls_tok   = (const float*)d_in[6];
    const float* ln_pre_s  = (const float*)d_in[7];
    const float* ln_pre_b  = (const float*)d_in[8];
    const float* norm1_s   = (const float*)d_in[9];
    const float* norm1_b   = (const float*)d_in[10];
    const float* in_proj_w = (const float*)d_in[11];
    const float* in_proj_b = (const float*)d_in[12];
    const float* out_proj_w= (const float*)d_in[13];
    const float* out_proj_b= (const float*)d_in[14];
    const float* norm2_s   = (const float*)d_in[15];
    const float* norm2_b   = (const float*)d_in[16];
    const float* ff_w1     = (const float*)d_in[17];
    const float* ff_b1     = (const float*)d_in[18];
    const float* ff_w2     = (const float*)d_in[19];
    const float* ff_b2     = (const float*)d_in[20];
    const float* ln_post_s = (const float*)d_in[21];
    const float* ln_post_b = (const float*)d_in[22];
    const float* dec_w1    = (const float*)d_in[23];
    const float* dec_b1    = (const float*)d_in[24];
    const float* dec_w2    = (const float*)d_in[25];
    const float* dec_b2    = (const float*)d_in[26];
    const float* dec_w3    = (const float*)d_in[27];
    const float* dec_b3    = (const float*)d_in[28];

    float* ws   = (float*)d_ws;
    float* y    = ws + F_Y;
    float* agg  = ws + F_AGG;
    float* xd   = ws + F_XD;
    float* cls  = ws + F_CLS;
    float* dd1  = ws + F_D1;
    float* dd2  = ws + F_D2;
    float* wpad = ws + F_WPAD;
    float* dinv = ws + F_DINV;
    int* ibase  = (int*)(ws + F_IEND);
    int* indeg  = ibase;
    int* offs   = ibase + N_NODES;
    int* cursor = offs + N_NODES + 1;
    int* csr    = cursor + N_NODES;
    uintptr_t ub = ((uintptr_t)(csr + NEDGE) + 15) & ~(uintptr_t)15;
    __bf16* h1b  = (__bf16*)ub;                          // [MROWS,256] (also attention O)
    __bf16* qkvb = h1b  + (size_t)MROWS * 256;           // [MROWS,768]
    __bf16* ffbb = qkvb + (size_t)MROWS * 768;           // [MROWS,1024]
    __bf16* wt_in  = ffbb  + (size_t)MROWS * 1024;       // 2 x 768*256
    __bf16* wt_out = wt_in  + 2 * 768 * 256;             // 2 x 256*256
    __bf16* wt_f1  = wt_out + 2 * 256 * 256;             // 2 x 1024*256
    __bf16* wt_f2  = wt_f1  + 2 * 1024 * 256;            // 2 x 256*1024

    // GCN prelude
    hipMemsetAsync(indeg, 0, N_NODES * sizeof(int), stream);
    hist_kernel<<<NEDGE / 256, 256, 0, stream>>>(ei + NEDGE, indeg);
    scan_kernel<<<1, 1024, 0, stream>>>(indeg, offs, cursor, dinv);
    fill_kernel<<<NEDGE / 256, 256, 0, stream>>>(ei, cursor, csr);
    y_kernel<<<N_NODES * 64 / 256, 256, 0, stream>>>(x, p, dinv, y);
    agg_kernel<<<N_NODES / 4, 256, 0, stream>>>(y, dinv, offs, csr, agg);
    wpad_kernel<<<64, 256, 0, stream>>>(gcn_w, wpad);

    // weight transpose+cast (once per call)
    for (int l = 0; l < 2; ++l) {
        tcast_kernel<<<dim3(4, 12), 256, 0, stream>>>(in_proj_w + (size_t)l * 256 * 768,
                                                      wt_in + (size_t)l * 768 * 256, 256, 768);
        tcast_kernel<<<dim3(4, 4), 256, 0, stream>>>(out_proj_w + (size_t)l * 256 * 256,
                                                     wt_out + (size_t)l * 256 * 256, 256, 256);
        tcast_kernel<<<dim3(4, 16), 256, 0, stream>>>(ff_w1 + (size_t)l * 256 * 1024,
                                                      wt_f1 + (size_t)l * 1024 * 256, 256, 1024);
        tcast_kernel<<<dim3(16, 4), 256, 0, stream>>>(ff_w2 + (size_t)l * 1024 * 256,
                                                      wt_f2 + (size_t)l * 256 * 1024, 1024, 256);
    }

    // GCN matmul -> xd rows (remapped past cls slots), fp32
    gemm_std<0, false, true><<<dim3(256, 4), 256, 0, stream>>>(agg, 64, wpad, 256, gcn_b, xd, 256, 64);
    cls_write<<<64, 256, 0, stream>>>(cls_tok, xd);
    ln4_kernel<0><<<MROWS / 4, 256, 0, stream>>>(xd, 256, xd, ln_pre_s, ln_pre_b);

    const int MB = (MROWS + 127) / 128;            // 129 m-tiles (BM=128)
    const int MG8 = (MB + 7) / 8;                  // 17 swizzle groups
    for (int l = 0; l < 2; ++l) {
        ln4_kernel<1><<<MROWS / 4, 256, 0, stream>>>(xd, 256, h1b, norm1_s + l * WDIM, norm1_b + l * WDIM);
        gemm_bf<128, 0, 0><<<8 * 6 * MG8, 256, 0, stream>>>(
            h1b, 256, wt_in + (size_t)l * 768 * 256, in_proj_b + l * 768, qkvb, 768, 256, MROWS, MB, 6);
        attn_mfma<<<512, 256, 0, stream>>>(qkvb, h1b);
        gemm_bf<64, 0, 1><<<8 * 4 * MG8, 256, 0, stream>>>(
            h1b, 256, wt_out + (size_t)l * 256 * 256, out_proj_b + l * WDIM, xd, 256, 256, MROWS, MB, 4);
        ln4_kernel<1><<<MROWS / 4, 256, 0, stream>>>(xd, 256, h1b, norm2_s + l * WDIM, norm2_b + l * WDIM);
        gemm_bf<128, 1, 0><<<8 * 8 * MG8, 256, 0, stream>>>(
            h1b, 256, wt_f1 + (size_t)l * 1024 * 256, ff_b1 + l * DFF, ffbb, 1024, 256, MROWS, MB, 8);
        gemm_bf<64, 1, 1><<<8 * 4 * MG8, 256, 0, stream>>>(
            ffbb, 1024, wt_f2 + (size_t)l * 256 * 1024, ff_b2 + l * WDIM, xd, 256, 1024, MROWS, MB, 4);
    }

    // cls extract + ln_post + decoder
    ln4_kernel<0><<<BGRAPH / 4, 256, 0, stream>>>(xd, SEQ * WDIM, cls, ln_post_s, ln_post_b);
    dec_fc2<256, 512><<<dim3(BGRAPH, 8), 256, 0, stream>>>(cls, dec_w1, dec_b1, dd1);
    dec_fc2<512, 512><<<dim3(BGRAPH, 8), 256, 0, stream>>>(dd1, dec_w2, dec_b2, dd2);
    dec_fc2<512, 64><<<dim3(BGRAPH, 1), 256, 0, stream>>>(dd2, dec_w3, dec_b3, (float*)d_out);
}

// Round 13
// 635.001 us; speedup vs baseline: 1.5118x; 1.1251x over previous
//
#include <hip/hip_runtime.h>
#include <math.h>

// ---------------- model dims ----------------
constexpr int N_NODES = 16384;
constexpr int BGRAPH  = 64;
constexpr int NEDGE   = 524288;
constexpr int SEQ     = 257;           // NPG + cls
constexpr int WDIM    = 256;
constexpr int DFF     = 1024;
constexpr int HID     = 512;
constexpr int MROWS   = BGRAPH * SEQ;  // 16448

// ---------------- ws layout (float offsets for fp32 region) ----------------
constexpr size_t F_Y    = 0;                                   // [N,64]
constexpr size_t F_AGG  = F_Y    + (size_t)N_NODES * 64;       // [N,64]
constexpr size_t F_XD   = F_AGG  + (size_t)N_NODES * 64;       // [16448,256] residual (fp32)
constexpr size_t F_CLS  = F_XD   + (size_t)MROWS * WDIM;       // [64,256]
constexpr size_t F_D1   = F_CLS  + (size_t)BGRAPH * WDIM;      // [64,512]
constexpr size_t F_D2   = F_D1   + (size_t)BGRAPH * HID;       // [64,512]
constexpr size_t F_WPAD = F_D2   + (size_t)BGRAPH * HID;       // [64,256]
constexpr size_t F_DINV = F_WPAD + (size_t)64 * WDIM;          // [N]
constexpr size_t F_XCLS = F_DINV + (size_t)N_NODES;            // [64,256] fp32 cls residual
constexpr size_t F_IEND = F_XCLS + (size_t)BGRAPH * WDIM;

typedef __attribute__((ext_vector_type(8))) __bf16 bf16x8;
typedef __attribute__((ext_vector_type(4))) __bf16 bf16x4;
typedef __attribute__((ext_vector_type(4))) float f32x4;

__device__ __forceinline__ float gelu_f(float x) {
    float u = 0.7978845608028654f * (x + 0.044715f * x * x * x);
    return 0.5f * x * (1.0f + tanhf(u));
}

// ---------------- GCN prelude ----------------
__global__ __launch_bounds__(256) void hist_kernel(const int* __restrict__ col, int* __restrict__ indeg) {
    int e = blockIdx.x * 256 + threadIdx.x;
    atomicAdd(&indeg[col[e]], 1);
}

__global__ __launch_bounds__(1024) void scan_kernel(const int* __restrict__ indeg, int* __restrict__ offs,
                                                    int* __restrict__ cursor, float* __restrict__ dinv) {
    __shared__ int parts[1024];
    int t = threadIdx.x;
    int base = t * 16;
    int loc[16];
    int s = 0;
#pragma unroll
    for (int i = 0; i < 16; ++i) { loc[i] = indeg[base + i]; s += loc[i]; }
    parts[t] = s;
    __syncthreads();
    for (int off = 1; off < 1024; off <<= 1) {
        int v = (t >= off) ? parts[t - off] : 0;
        __syncthreads();
        parts[t] += v;
        __syncthreads();
    }
    int run = (t == 0) ? 0 : parts[t - 1];
#pragma unroll
    for (int i = 0; i < 16; ++i) {
        offs[base + i] = run;
        cursor[base + i] = run;
        dinv[base + i] = rsqrtf((float)loc[i] + 1.0f);  // deg = indeg + self-loop
        run += loc[i];
    }
    if (t == 1023) offs[N_NODES] = run;
}

__global__ __launch_bounds__(256) void fill_kernel(const int* __restrict__ ei, int* __restrict__ cursor,
                                                   int* __restrict__ csr) {
    int e = blockIdx.x * 256 + threadIdx.x;
    int r = ei[e];            // source
    int c = ei[NEDGE + e];    // destination
    int pos = atomicAdd(&cursor[c], 1);
    csr[pos] = r;
}

// xc = [x(32) | sin(p*2^j*pi)(24) | 0(8)], pre-scaled by dinv[node]
__global__ __launch_bounds__(256) void y_kernel(const float* __restrict__ x, const float* __restrict__ p,
                                                const float* __restrict__ dinv, float* __restrict__ y) {
    int idx = blockIdx.x * 256 + threadIdx.x;
    int i = idx >> 6, d = idx & 63;
    float v = 0.f;
    if (d < 32) {
        v = x[i * 32 + d];
    } else if (d < 56) {
        int dd = d - 32;
        int dim = dd >> 3, j = dd & 7;
        v = sinf(p[i * 3 + dim] * (3.14159265358979323846f * (float)(1 << j)));
    }
    y[idx] = dinv[i] * v;
}

// agg[c] = dinv[c] * (y[c] + sum_{in-edges} y[src])   (wave per node)
__global__ __launch_bounds__(256) void agg_kernel(const float* __restrict__ y, const float* __restrict__ dinv,
                                                  const int* __restrict__ offs, const int* __restrict__ csr,
                                                  float* __restrict__ agg) {
    int c = (blockIdx.x * 256 + threadIdx.x) >> 6;
    int lane = threadIdx.x & 63;
    float acc = y[(size_t)c * 64 + lane];
    int s = offs[c], e = offs[c + 1];
    for (int j = s; j < e; ++j) {
        int r = csr[j];
        acc += y[(size_t)r * 64 + lane];
    }
    agg[(size_t)c * 64 + lane] = dinv[c] * acc;
}

__global__ __launch_bounds__(256) void wpad_kernel(const float* __restrict__ w, float* __restrict__ wp) {
    int idx = blockIdx.x * 256 + threadIdx.x;
    wp[idx] = (idx < 56 * 256) ? w[idx] : 0.f;
}

__global__ __launch_bounds__(256) void cls_write(const float* __restrict__ tok, float* __restrict__ xd) {
    xd[(size_t)blockIdx.x * SEQ * WDIM + threadIdx.x] = tok[threadIdx.x];
}

// ---------------- LayerNorm: wave per row, 4 rows/block, no barriers ----------------
template <int OUTBF>
__global__ __launch_bounds__(256) void ln4_kernel(const float* __restrict__ in, int rin_stride,
                                                  void* __restrict__ out,
                                                  const float* __restrict__ g, const float* __restrict__ be) {
    int w = threadIdx.x >> 6, lane = threadIdx.x & 63;
    int row = blockIdx.x * 4 + w;
    const float* ip = in + (size_t)row * rin_stride + lane * 4;
    f32x4 v = *(const f32x4*)ip;
    float s = v[0] + v[1] + v[2] + v[3];
    float ss = v[0] * v[0] + v[1] * v[1] + v[2] * v[2] + v[3] * v[3];
#pragma unroll
    for (int off = 1; off < 64; off <<= 1) { s += __shfl_xor(s, off); ss += __shfl_xor(ss, off); }
    float mean = s * 0.00390625f;
    float var = ss * 0.00390625f - mean * mean;
    float rs = rsqrtf(var + 1e-5f);
    f32x4 gv = *(const f32x4*)(g + lane * 4);
    f32x4 bv = *(const f32x4*)(be + lane * 4);
    if (OUTBF) {
        bf16x4 o;
#pragma unroll
        for (int i = 0; i < 4; ++i) o[i] = (__bf16)((v[i] - mean) * rs * gv[i] + bv[i]);
        *(bf16x4*)((__bf16*)out + (size_t)row * 256 + lane * 4) = o;
    } else {
        f32x4 o;
#pragma unroll
        for (int i = 0; i < 4; ++i) o[i] = (v[i] - mean) * rs * gv[i] + bv[i];
        *(f32x4*)((float*)out + (size_t)row * 256 + lane * 4) = o;
    }
}

// ---------------- weight transpose+cast: W[K][N] fp32 -> Wt[N][K] bf16 ----------------
__global__ __launch_bounds__(256) void tcast_kernel(const float* __restrict__ W, __bf16* __restrict__ Wt,
                                                    int K, int N) {
    __shared__ __bf16 T[64][65];
    int t = threadIdx.x;
    int k0 = blockIdx.x << 6, n0 = blockIdx.y << 6;
#pragma unroll
    for (int i = 0; i < 16; ++i) {
        int idx = t + i * 256;
        int k = idx >> 6, n = idx & 63;
        T[k][n] = (__bf16)W[(size_t)(k0 + k) * N + n0 + n];
    }
    __syncthreads();
#pragma unroll
    for (int i = 0; i < 16; ++i) {
        int idx = t + i * 256;
        int n = idx >> 6, k = idx & 63;
        Wt[(size_t)(n0 + n) * K + k0 + k] = T[k][n];
    }
}

// ---------------- bf16 MFMA GEMM: BM=128, BN in {128,64}, BK=64 per barrier-pair ----------------
// (round-12 kernel, unchanged — ties the best measured GEMM at ~61 us/dispatch)
constexpr int LP = 36;
template <int BN, int ACT, int OMODE>
__global__ __launch_bounds__(256) void gemm_bf(const __bf16* __restrict__ A, int lda,
                                               const __bf16* __restrict__ Bt,
                                               const float* __restrict__ bias,
                                               void* __restrict__ Cv, int ldc,
                                               int Ktot, int Mrows, int MBlocks, int NY) {
    constexpr int NTW = BN / 32;       // n-tiles per wave
    constexpr int AH = 128 * LP;       // A half-buffer stride (elements)
    constexpr int BH = BN * LP;        // B half-buffer stride
    __shared__ __bf16 As[2 * 128 * LP];
    __shared__ __bf16 Bs[2 * BN * LP];
    int f = blockIdx.x;
    int m8 = f & 7;
    int rest = f >> 3;
    int mg = rest / NY;
    int yb = rest - mg * NY;
    int mb = mg * 8 + m8;
    if (mb >= MBlocks) return;
    int m0 = mb << 7, n0 = yb * BN;

    int t = threadIdx.x;
    int w = t >> 6, L = t & 63;
    int wm = w >> 1, wn = w & 1;
    int lc = L & 15, quad = L >> 4;

    int sa_row = t >> 1, sa_off = (t & 1) << 4;
    const __bf16* ap = A + (size_t)(m0 + sa_row) * lda + sa_off;
    __bf16* as_dst = &As[sa_row * LP + sa_off];
    const __bf16* bp;
    __bf16* bs_dst;
    if constexpr (BN == 128) {
        bp = Bt + (size_t)(n0 + sa_row) * Ktot + sa_off;
        bs_dst = &Bs[sa_row * LP + sa_off];
    } else {
        int sb_row = t >> 2, sb_off = (t & 3) << 3;
        bp = Bt + (size_t)(n0 + sb_row) * Ktot + sb_off;
        bs_dst = &Bs[sb_row * LP + sb_off];
    }

    int a_base = (wm * 64 + lc) * LP + quad * 8;
    int b_base = (wn * (BN / 2) + lc) * LP + quad * 8;

    f32x4 acc[4][NTW] = {};

    bf16x8 ea0, ea1, eb0, eb1, oa0, oa1, ob0, ob1;
    ea0 = *(const bf16x8*)(ap);        ea1 = *(const bf16x8*)(ap + 8);
    oa0 = *(const bf16x8*)(ap + 32);   oa1 = *(const bf16x8*)(ap + 40);
    if constexpr (BN == 128) {
        eb0 = *(const bf16x8*)(bp);        eb1 = *(const bf16x8*)(bp + 8);
        ob0 = *(const bf16x8*)(bp + 32);   ob1 = *(const bf16x8*)(bp + 40);
    } else {
        eb0 = *(const bf16x8*)(bp);
        ob0 = *(const bf16x8*)(bp + 32);
    }

    for (int k0 = 0; k0 < Ktot; k0 += 64) {
        __syncthreads();
        *(bf16x8*)as_dst = ea0;
        *(bf16x8*)(as_dst + 8) = ea1;
        *(bf16x8*)(as_dst + AH) = oa0;
        *(bf16x8*)(as_dst + AH + 8) = oa1;
        if constexpr (BN == 128) {
            *(bf16x8*)bs_dst = eb0;
            *(bf16x8*)(bs_dst + 8) = eb1;
            *(bf16x8*)(bs_dst + BH) = ob0;
            *(bf16x8*)(bs_dst + BH + 8) = ob1;
        } else {
            *(bf16x8*)bs_dst = eb0;
            *(bf16x8*)(bs_dst + BH) = ob0;
        }
        __syncthreads();
        if (k0 + 64 < Ktot) {
            ea0 = *(const bf16x8*)(ap + k0 + 64);
            ea1 = *(const bf16x8*)(ap + k0 + 72);
            oa0 = *(const bf16x8*)(ap + k0 + 96);
            oa1 = *(const bf16x8*)(ap + k0 + 104);
            if constexpr (BN == 128) {
                eb0 = *(const bf16x8*)(bp + k0 + 64);
                eb1 = *(const bf16x8*)(bp + k0 + 72);
                ob0 = *(const bf16x8*)(bp + k0 + 96);
                ob1 = *(const bf16x8*)(bp + k0 + 104);
            } else {
                eb0 = *(const bf16x8*)(bp + k0 + 64);
                ob0 = *(const bf16x8*)(bp + k0 + 96);
            }
        }
        {
            bf16x8 af[4], bfr[NTW];
#pragma unroll
            for (int i = 0; i < 4; ++i) af[i] = *(const bf16x8*)&As[a_base + i * 16 * LP];
#pragma unroll
            for (int i = 0; i < NTW; ++i) bfr[i] = *(const bf16x8*)&Bs[b_base + i * 16 * LP];
#pragma unroll
            for (int mt = 0; mt < 4; ++mt)
#pragma unroll
                for (int nt = 0; nt < NTW; ++nt)
                    acc[mt][nt] = __builtin_amdgcn_mfma_f32_16x16x32_bf16(af[mt], bfr[nt], acc[mt][nt], 0, 0, 0);
        }
        {
            bf16x8 af[4], bfr[NTW];
#pragma unroll
            for (int i = 0; i < 4; ++i) af[i] = *(const bf16x8*)&As[AH + a_base + i * 16 * LP];
#pragma unroll
            for (int i = 0; i < NTW; ++i) bfr[i] = *(const bf16x8*)&Bs[BH + b_base + i * 16 * LP];
#pragma unroll
            for (int mt = 0; mt < 4; ++mt)
#pragma unroll
                for (int nt = 0; nt < NTW; ++nt)
                    acc[mt][nt] = __builtin_amdgcn_mfma_f32_16x16x32_bf16(af[mt], bfr[nt], acc[mt][nt], 0, 0, 0);
        }
    }

#pragma unroll
    for (int mt = 0; mt < 4; ++mt) {
        int gmb = m0 + wm * 64 + mt * 16 + quad * 4;
#pragma unroll
        for (int nt = 0; nt < NTW; ++nt) {
            int gn = n0 + wn * (BN / 2) + nt * 16 + lc;
            float bv = bias[gn];
#pragma unroll
            for (int r = 0; r < 4; ++r) {
                int gm = gmb + r;
                if (gm >= Mrows) continue;
                float v = acc[mt][nt][r] + bv;
                if (ACT == 1) v = gelu_f(v);
                if (OMODE == 0) {
                    ((__bf16*)Cv)[(size_t)gm * ldc + gn] = (__bf16)v;
                } else {
                    float* cp = (float*)Cv + (size_t)gm * ldc + gn;
                    *cp = v + *cp;
                }
            }
        }
    }
}

// ---------------- MFMA attention (layer 0 only) ----------------
constexpr int PPITCH = 284;
__global__ __launch_bounds__(256, 2) void attn_mfma(const __bf16* __restrict__ qkvb,
                                                    __bf16* __restrict__ obuf) {
    __shared__ __bf16 Vt[32][PPITCH];
    __shared__ __bf16 Pb[4][16][PPITCH];
    int bb = blockIdx.x;
    int b = bb >> 3, h = bb & 7;
    int t = threadIdx.x;
    int w = t >> 6, L = t & 63;
    int c = L & 15, quad = L >> 4;
    const float scale = 0.17677669529663687f;  // 1/sqrt(32)
    const __bf16* qb = qkvb + (size_t)(b * SEQ) * 768 + h * 32;
    const __bf16* kb = qb + 256;
    const __bf16* vb = qb + 512;
    __bf16* ob = obuf + (size_t)(b * SEQ) * 256 + h * 32;

    for (int idx = t; idx < 272 * 4; idx += 256) {
        int key = idx >> 2, dc = (idx & 3) * 8;
        bf16x8 vv = {};
        if (key < SEQ) vv = *(const bf16x8*)(vb + (size_t)key * 768 + dc);
#pragma unroll
        for (int j = 0; j < 8; ++j) Vt[dc + j][key] = vv[j];
    }

    bf16x8 kfr[17];
#pragma unroll
    for (int tt = 0; tt < 17; ++tt) {
        int kr = tt * 16 + c; if (kr > 256) kr = 256;
        kfr[tt] = *(const bf16x8*)(kb + (size_t)kr * 768 + quad * 8);
    }
    __syncthreads();

#pragma unroll 1
    for (int qt = 0; qt < 5; ++qt) {
        int q0 = qt * 64 + w * 16;
        if (q0 > 256) continue;
        int ntiles = (qt == 0 && w == 0) ? 17 : (qt * 4 + w + 1);
        if (ntiles > 17) ntiles = 17;
        int nkc = (ntiles + 1) >> 1;

        bf16x8 qf;
        {
            int qr = q0 + c; if (qr > 256) qr = 256;
            qf = *(const bf16x8*)(qb + (size_t)qr * 768 + quad * 8);
        }

        f32x4 acc[17];
#pragma unroll
        for (int tt = 0; tt < 17; ++tt) {
            if (tt >= ntiles) continue;
            f32x4 z = {0.f, 0.f, 0.f, 0.f};
            acc[tt] = __builtin_amdgcn_mfma_f32_16x16x32_bf16(qf, kfr[tt], z, 0, 0, 0);
        }

        float inv[4];
#pragma unroll
        for (int j = 0; j < 4; ++j) {
            int q = q0 + quad * 4 + j;
            float mx = -3.0e38f;
#pragma unroll
            for (int tt = 0; tt < 17; ++tt) {
                if (tt >= ntiles) continue;
                int key = tt * 16 + c;
                bool ok = (key < SEQ) && (q == 0 || key <= q);
                float v = ok ? acc[tt][j] * scale : -3.0e38f;
                mx = fmaxf(mx, v);
            }
            mx = fmaxf(mx, __shfl_xor(mx, 1));
            mx = fmaxf(mx, __shfl_xor(mx, 2));
            mx = fmaxf(mx, __shfl_xor(mx, 4));
            mx = fmaxf(mx, __shfl_xor(mx, 8));
            float s = 0.f;
#pragma unroll
            for (int tt = 0; tt < 17; ++tt) {
                if (tt >= ntiles) continue;
                int key = tt * 16 + c;
                bool ok = (key < SEQ) && (q == 0 || key <= q);
                float pv = ok ? expf(acc[tt][j] * scale - mx) : 0.f;
                s += pv;
                Pb[w][quad * 4 + j][key] = (__bf16)pv;
            }
            if ((ntiles & 1) && ntiles < 17)
                Pb[w][quad * 4 + j][ntiles * 16 + c] = (__bf16)0.f;
            s += __shfl_xor(s, 1);
            s += __shfl_xor(s, 2);
            s += __shfl_xor(s, 4);
            s += __shfl_xor(s, 8);
            inv[j] = 1.0f / s;
        }

        f32x4 oacc0 = {0.f, 0.f, 0.f, 0.f};
        f32x4 oacc1 = {0.f, 0.f, 0.f, 0.f};
#pragma unroll
        for (int kc = 0; kc < 9; ++kc) {
            if (kc >= nkc) continue;
            int off = kc * 32 + quad * 8;
            bf16x8 af = {};
            bf16x8 bf0 = {};
            bf16x8 bf1 = {};
            if (off < 257) {
                af  = *(const bf16x8*)&Pb[w][c][off];
                bf0 = *(const bf16x8*)&Vt[c][off];
                bf1 = *(const bf16x8*)&Vt[16 + c][off];
            }
            oacc0 = __builtin_amdgcn_mfma_f32_16x16x32_bf16(af, bf0, oacc0, 0, 0, 0);
            oacc1 = __builtin_amdgcn_mfma_f32_16x16x32_bf16(af, bf1, oacc1, 0, 0, 0);
        }

#pragma unroll
        for (int j = 0; j < 4; ++j) {
            int q = q0 + quad * 4 + j;
            if (q < SEQ) {
                __bf16* op = ob + (size_t)q * 256;
                op[c]      = (__bf16)(oacc0[j] * inv[j]);
                op[16 + c] = (__bf16)(oacc1[j] * inv[j]);
            }
        }
    }
}

// ---------------- layer-1 pruned cls path (only 64 cls rows matter) ----------------
// Q projection for cls rows: qcls[b][col] = h1b[cls row b] . in_proj_w_l1[:, col] + bias
__global__ __launch_bounds__(256) void qcls_kernel(const __bf16* __restrict__ h1b,
                                                   const float* __restrict__ W,     // in_proj_w + l1
                                                   const float* __restrict__ bias,  // in_proj_b + 768
                                                   __bf16* __restrict__ qcls) {
    __shared__ float hrow[256];
    int b = blockIdx.x, t = threadIdx.x;
    hrow[t] = (float)h1b[(size_t)(b * SEQ) * 256 + t];
    __syncthreads();
    float s = bias[t];
    for (int k = 0; k < 256; ++k) s += hrow[k] * W[(size_t)k * 768 + t];
    qcls[b * 256 + t] = (__bf16)s;
}

// cls attention: one wave per (graph, head); cls row is fully unmasked.
__global__ __launch_bounds__(64) void attn_cls(const __bf16* __restrict__ qcls,
                                               const __bf16* __restrict__ qkvb,
                                               __bf16* __restrict__ ocls) {
    __shared__ float p[260];
    int bb = blockIdx.x;
    int b = bb >> 3, h = bb & 7;
    int lane = threadIdx.x;
    const float scale = 0.17677669529663687f;
    float q[32];
    const __bf16* qp = qcls + b * 256 + h * 32;
#pragma unroll
    for (int c = 0; c < 4; ++c) {
        bf16x8 v = *(const bf16x8*)(qp + c * 8);
#pragma unroll
        for (int e = 0; e < 8; ++e) q[c * 8 + e] = (float)v[e];
    }
    float sc[5];
    float mx = -3.0e38f;
#pragma unroll
    for (int i = 0; i < 5; ++i) {
        int j = lane + i * 64;
        float s = -3.0e38f;
        if (j < SEQ) {
            const __bf16* kp = qkvb + (size_t)(b * SEQ + j) * 768 + 256 + h * 32;
            float a = 0.f;
#pragma unroll
            for (int c = 0; c < 4; ++c) {
                bf16x8 v = *(const bf16x8*)(kp + c * 8);
#pragma unroll
                for (int e = 0; e < 8; ++e) a += q[c * 8 + e] * (float)v[e];
            }
            s = a * scale;
        }
        sc[i] = s;
        mx = fmaxf(mx, s);
    }
#pragma unroll
    for (int off = 1; off < 64; off <<= 1) mx = fmaxf(mx, __shfl_xor(mx, off));
    float sum = 0.f;
#pragma unroll
    for (int i = 0; i < 5; ++i) {
        int j = lane + i * 64;
        float e = (j < SEQ) ? expf(sc[i] - mx) : 0.f;
        sc[i] = e;
        sum += e;
    }
#pragma unroll
    for (int off = 1; off < 64; off <<= 1) sum += __shfl_xor(sum, off);
    float inv = 1.0f / sum;
#pragma unroll
    for (int i = 0; i < 5; ++i) {
        int j = lane + i * 64;
        if (j < SEQ) p[j] = sc[i] * inv;
    }
    __syncthreads();
    if (lane < 32) {
        float o = 0.f;
        for (int j = 0; j < SEQ; ++j)
            o += p[j] * (float)qkvb[(size_t)(b * SEQ + j) * 768 + 512 + h * 32 + lane];
        ocls[b * 256 + h * 32 + lane] = (__bf16)o;
    }
}

// out_proj for cls rows: xcls = xd[cls row] + ocls . W + b
__global__ __launch_bounds__(256) void oproj_cls(const __bf16* __restrict__ ocls,
                                                 const float* __restrict__ W,     // out_proj_w + l1
                                                 const float* __restrict__ bias,  // out_proj_b + 256
                                                 const float* __restrict__ xd,
                                                 float* __restrict__ xcls) {
    __shared__ float orow[256];
    int b = blockIdx.x, t = threadIdx.x;
    orow[t] = (float)ocls[b * 256 + t];
    __syncthreads();
    float s = bias[t];
    for (int k = 0; k < 256; ++k) s += orow[k] * W[(size_t)k * 256 + t];
    xcls[b * 256 + t] = s + xd[(size_t)(b * SEQ) * 256 + t];
}

// ff1 for cls rows: f1cls = gelu(h2cls . W1 + b1)   (4 cols/thread)
__global__ __launch_bounds__(256) void ff1_cls(const __bf16* __restrict__ h2cls,
                                               const float* __restrict__ W1,  // ff_w1 + l1
                                               const float* __restrict__ b1,  // ff_b1 + 1024
                                               __bf16* __restrict__ f1cls) {
    __shared__ float hrow[256];
    int b = blockIdx.x, t = threadIdx.x;
    hrow[t] = (float)h2cls[b * 256 + t];
    __syncthreads();
#pragma unroll
    for (int i = 0; i < 4; ++i) {
        int col = t + i * 256;
        float s = b1[col];
        for (int k = 0; k < 256; ++k) s += hrow[k] * W1[(size_t)k * 1024 + col];
        f1cls[b * 1024 + col] = (__bf16)gelu_f(s);
    }
}

// ff2 for cls rows: xcls += gelu(f1cls . W2 + b2)
__global__ __launch_bounds__(256) void ff2_cls(const __bf16* __restrict__ f1cls,
                                               const float* __restrict__ W2,  // ff_w2 + l1
                                               const float* __restrict__ b2,  // ff_b2 + 256
                                               float* __restrict__ xcls) {
    __shared__ float frow[1024];
    int b = blockIdx.x, t = threadIdx.x;
#pragma unroll
    for (int i = 0; i < 4; ++i) frow[t + i * 256] = (float)f1cls[b * 1024 + t + i * 256];
    __syncthreads();
    float s = b2[t];
    for (int k = 0; k < 1024; ++k) s += frow[k] * W2[(size_t)k * 256 + t];
    xcls[b * 256 + t] += gelu_f(s);
}

// ---------------- fp32 tiled GEMM (kept for GCN projection) ----------------
template <int ACT, bool RESID, bool REMAP>
__global__ __launch_bounds__(256) void gemm_std(const float* __restrict__ A, int lda,
                                                const float* __restrict__ Bw, int ldb,
                                                const float* __restrict__ bias,
                                                float* __restrict__ C, int ldc, int Ktot) {
    int t = threadIdx.x;
    int m0 = blockIdx.x << 6, n0 = blockIdx.y << 6;
    __shared__ float As[16][68];
    __shared__ float Bs[16][64];
    int arow = t >> 2, akk = (t & 3) << 2;
    int bk = t >> 4, bn = (t & 15) << 2;
    int tm = (t >> 4) << 2, tn = (t & 15) << 2;
    float acc[4][4] = {};
    const float* ap = A + (size_t)(m0 + arow) * lda + akk;
    const float* bp = Bw + (size_t)bk * ldb + n0 + bn;
    for (int k0 = 0; k0 < Ktot; k0 += 16) {
        float4 av = *(const float4*)(ap + k0);
        float4 bv = *(const float4*)(bp + (size_t)k0 * ldb);
        __syncthreads();
        As[akk + 0][arow] = av.x; As[akk + 1][arow] = av.y;
        As[akk + 2][arow] = av.z; As[akk + 3][arow] = av.w;
        *(float4*)&Bs[bk][bn] = bv;
        __syncthreads();
#pragma unroll
        for (int k = 0; k < 16; ++k) {
            float4 a = *(const float4*)&As[k][tm];
            float4 b = *(const float4*)&Bs[k][tn];
            acc[0][0] += a.x * b.x; acc[0][1] += a.x * b.y; acc[0][2] += a.x * b.z; acc[0][3] += a.x * b.w;
            acc[1][0] += a.y * b.x; acc[1][1] += a.y * b.y; acc[1][2] += a.y * b.z; acc[1][3] += a.y * b.w;
            acc[2][0] += a.z * b.x; acc[2][1] += a.z * b.y; acc[2][2] += a.z * b.z; acc[2][3] += a.z * b.w;
            acc[3][0] += a.w * b.x; acc[3][1] += a.w * b.y; acc[3][2] += a.w * b.z; acc[3][3] += a.w * b.w;
        }
    }
#pragma unroll
    for (int i = 0; i < 4; ++i) {
        int gm = m0 + tm + i;
        int orow = REMAP ? (gm + (gm >> 8) + 1) : gm;  // node -> xd row (skip cls slots)
        float* cp = C + (size_t)orow * ldc + n0 + tn;
        float4 r;
        r.x = acc[i][0] + bias[n0 + tn + 0];
        r.y = acc[i][1] + bias[n0 + tn + 1];
        r.z = acc[i][2] + bias[n0 + tn + 2];
        r.w = acc[i][3] + bias[n0 + tn + 3];
        if (ACT == 1) { r.x = gelu_f(r.x); r.y = gelu_f(r.y); r.z = gelu_f(r.z); r.w = gelu_f(r.w); }
        if (ACT == 2) { r.x = fmaxf(r.x, 0.f); r.y = fmaxf(r.y, 0.f); r.z = fmaxf(r.z, 0.f); r.w = fmaxf(r.w, 0.f); }
        if (RESID) {
            float4 o = *(const float4*)cp;
            r.x += o.x; r.y += o.y; r.z += o.z; r.w += o.w;
        }
        *(float4*)cp = r;
    }
}

// ---------------- decoder FC: grid (sample, out-chunk), 4 waves split K ----------------
template <int K, int NOUT>
__global__ __launch_bounds__(256) void dec_fc2(const float* __restrict__ in, const float* __restrict__ w,
                                               const float* __restrict__ bia, float* __restrict__ out) {
    __shared__ float rowbuf[K];
    __shared__ float part[4][64];
    int b = blockIdx.x, c = blockIdx.y, t = threadIdx.x;
    for (int i = t; i < K; i += 256) rowbuf[i] = in[(size_t)b * K + i];
    __syncthreads();
    int lane = t & 63, wv = t >> 6;
    int n = c * 64 + lane;
    const int KQ = K / 4;
    const float* wp = w + (size_t)(wv * KQ) * NOUT + n;
    float s = 0.f;
#pragma unroll 8
    for (int k = 0; k < KQ; ++k) s += rowbuf[wv * KQ + k] * wp[(size_t)k * NOUT];
    part[wv][lane] = s;
    __syncthreads();
    if (wv == 0) {
        float r = part[0][lane] + part[1][lane] + part[2][lane] + part[3][lane] + bia[n];
        out[(size_t)b * NOUT + n] = fmaxf(r, 0.f);
    }
}

// ---------------- launch ----------------
extern "C" void kernel_launch(void* const* d_in, const int* in_sizes, int n_in,
                              void* d_out, int out_size, void* d_ws, size_t ws_size,
                              hipStream_t stream) {
    const float* x         = (const float*)d_in[0];
    const float* p         = (const float*)d_in[1];
    const int*   ei        = (const int*)d_in[2];
    const float* gcn_w     = (const float*)d_in[4];
    const float* gcn_b     = (const float*)d_in[5];
    const float* cls_tok   = (const float*)d_in[6];
    const float* ln_pre_s  = (const float*)d_in[7];
    const float* ln_pre_b  = (const float*)d_in[8];
    const float* norm1_s   = (const float*)d_in[9];
    const float* norm1_b   = (const float*)d_in[10];
    const float* in_proj_w = (const float*)d_in[11];
    const float* in_proj_b = (const float*)d_in[12];
    const float* out_proj_w= (const float*)d_in[13];
    const float* out_proj_b= (const float*)d_in[14];
    const float* norm2_s   = (const float*)d_in[15];
    const float* norm2_b   = (const float*)d_in[16];
    const float* ff_w1     = (const float*)d_in[17];
    const float* ff_b1     = (const float*)d_in[18];
    const float* ff_w2     = (const float*)d_in[19];
    const float* ff_b2     = (const float*)d_in[20];
    const float* ln_post_s = (const float*)d_in[21];
    const float* ln_post_b = (const float*)d_in[22];
    const float* dec_w1    = (const float*)d_in[23];
    const float* dec_b1    = (const float*)d_in[24];
    const float* dec_w2    = (const float*)d_in[25];
    const float* dec_b2    = (const float*)d_in[26];
    const float* dec_w3    = (const float*)d_in[27];
    const float* dec_b3    = (const float*)d_in[28];

    float* ws   = (float*)d_ws;
    float* y    = ws + F_Y;
    float* agg  = ws + F_AGG;
    float* xd   = ws + F_XD;
    float* cls  = ws + F_CLS;
    float* dd1  = ws + F_D1;
    float* dd2  = ws + F_D2;
    float* wpad = ws + F_WPAD;
    float* dinv = ws + F_DINV;
    float* xcls = ws + F_XCLS;
    int* ibase  = (int*)(ws + F_IEND);
    int* indeg  = ibase;
    int* offs   = ibase + N_NODES;
    int* cursor = offs + N_NODES + 1;
    int* csr    = cursor + N_NODES;
    uintptr_t ub = ((uintptr_t)(csr + NEDGE) + 15) & ~(uintptr_t)15;
    __bf16* h1b  = (__bf16*)ub;                          // [MROWS,256] (also attention O, layer 0)
    __bf16* qkvb = h1b  + (size_t)MROWS * 256;           // [MROWS,768]
    __bf16* ffbb = qkvb + (size_t)MROWS * 768;           // [MROWS,1024]
    __bf16* wt_in  = ffbb  + (size_t)MROWS * 1024;       // 2 x 768*256
    __bf16* wt_out = wt_in  + 2 * 768 * 256;             // 2 x 256*256 (l0 used)
    __bf16* wt_f1  = wt_out + 2 * 256 * 256;             // 2 x 1024*256 (l0 used)
    __bf16* wt_f2  = wt_f1  + 2 * 1024 * 256;            // 2 x 256*1024 (l0 used)
    __bf16* qcls   = wt_f2 + 2 * 256 * 1024;             // [64,256]
    __bf16* ocls   = qcls + 64 * 256;                    // [64,256]
    __bf16* h2cls  = ocls + 64 * 256;                    // [64,256]
    __bf16* f1cls  = h2cls + 64 * 256;                   // [64,1024]

    // GCN prelude
    hipMemsetAsync(indeg, 0, N_NODES * sizeof(int), stream);
    hist_kernel<<<NEDGE / 256, 256, 0, stream>>>(ei + NEDGE, indeg);
    scan_kernel<<<1, 1024, 0, stream>>>(indeg, offs, cursor, dinv);
    fill_kernel<<<NEDGE / 256, 256, 0, stream>>>(ei, cursor, csr);
    y_kernel<<<N_NODES * 64 / 256, 256, 0, stream>>>(x, p, dinv, y);
    agg_kernel<<<N_NODES / 4, 256, 0, stream>>>(y, dinv, offs, csr, agg);
    wpad_kernel<<<64, 256, 0, stream>>>(gcn_w, wpad);

    // weight transpose+cast: layer 0 all four; layer 1 only in_proj (for KV GEMM)
    tcast_kernel<<<dim3(4, 12), 256, 0, stream>>>(in_proj_w, wt_in, 256, 768);
    tcast_kernel<<<dim3(4, 4), 256, 0, stream>>>(out_proj_w, wt_out, 256, 256);
    tcast_kernel<<<dim3(4, 16), 256, 0, stream>>>(ff_w1, wt_f1, 256, 1024);
    tcast_kernel<<<dim3(16, 4), 256, 0, stream>>>(ff_w2, wt_f2, 1024, 256);
    tcast_kernel<<<dim3(4, 12), 256, 0, stream>>>(in_proj_w + (size_t)256 * 768,
                                                  wt_in + (size_t)768 * 256, 256, 768);

    // GCN matmul -> xd rows (remapped past cls slots), fp32
    gemm_std<0, false, true><<<dim3(256, 4), 256, 0, stream>>>(agg, 64, wpad, 256, gcn_b, xd, 256, 64);
    cls_write<<<64, 256, 0, stream>>>(cls_tok, xd);
    ln4_kernel<0><<<MROWS / 4, 256, 0, stream>>>(xd, 256, xd, ln_pre_s, ln_pre_b);

    const int MB = (MROWS + 127) / 128;            // 129 m-tiles (BM=128)
    const int MG8 = (MB + 7) / 8;                  // 17 swizzle groups

    // ---------------- layer 0 (full) ----------------
    ln4_kernel<1><<<MROWS / 4, 256, 0, stream>>>(xd, 256, h1b, norm1_s, norm1_b);
    gemm_bf<128, 0, 0><<<8 * 6 * MG8, 256, 0, stream>>>(
        h1b, 256, wt_in, in_proj_b, qkvb, 768, 256, MROWS, MB, 6);
    attn_mfma<<<512, 256, 0, stream>>>(qkvb, h1b);
    gemm_bf<64, 0, 1><<<8 * 4 * MG8, 256, 0, stream>>>(
        h1b, 256, wt_out, out_proj_b, xd, 256, 256, MROWS, MB, 4);
    ln4_kernel<1><<<MROWS / 4, 256, 0, stream>>>(xd, 256, h1b, norm2_s, norm2_b);
    gemm_bf<128, 1, 0><<<8 * 8 * MG8, 256, 0, stream>>>(
        h1b, 256, wt_f1, ff_b1, ffbb, 1024, 256, MROWS, MB, 8);
    gemm_bf<64, 1, 1><<<8 * 4 * MG8, 256, 0, stream>>>(
        ffbb, 1024, wt_f2, ff_b2, xd, 256, 1024, MROWS, MB, 4);

    // ---------------- layer 1 (pruned: only cls rows feed the output) ----------------
    // norm1 (full: K,V need all rows)
    ln4_kernel<1><<<MROWS / 4, 256, 0, stream>>>(xd, 256, h1b, norm1_s + WDIM, norm1_b + WDIM);
    // K,V projection for all rows (cols 256..768 of in_proj)
    gemm_bf<128, 0, 0><<<8 * 4 * MG8, 256, 0, stream>>>(
        h1b, 256, wt_in + (size_t)768 * 256 + (size_t)256 * 256,
        in_proj_b + 768 + 256, qkvb + 256, 768, 256, MROWS, MB, 4);
    // Q projection for cls rows only
    qcls_kernel<<<64, 256, 0, stream>>>(h1b, in_proj_w + (size_t)256 * 768, in_proj_b + 768, qcls);
    // cls attention (unmasked row 0 over all 257 keys)
    attn_cls<<<512, 64, 0, stream>>>(qcls, qkvb, ocls);
    // out_proj + residual -> xcls (fp32)
    oproj_cls<<<64, 256, 0, stream>>>(ocls, out_proj_w + (size_t)256 * 256, out_proj_b + 256, xd, xcls);
    // norm2 on 64 cls rows
    ln4_kernel<1><<<16, 256, 0, stream>>>(xcls, 256, h2cls, norm2_s + WDIM, norm2_b + WDIM);
    // ff1 / ff2 on cls rows
    ff1_cls<<<64, 256, 0, stream>>>(h2cls, ff_w1 + (size_t)256 * 1024, ff_b1 + 1024, f1cls);
    ff2_cls<<<64, 256, 0, stream>>>(f1cls, ff_w2 + (size_t)1024 * 256, ff_b2 + 256, xcls);

    // ln_post + decoder
    ln4_kernel<0><<<16, 256, 0, stream>>>(xcls, 256, cls, ln_post_s, ln_post_b);
    dec_fc2<256, 512><<<dim3(BGRAPH, 8), 256, 0, stream>>>(cls, dec_w1, dec_b1, dd1);
    dec_fc2<512, 512><<<dim3(BGRAPH, 8), 256, 0, stream>>>(dd1, dec_w2, dec_b2, dd2);
    dec_fc2<512, 64><<<dim3(BGRAPH, 1), 256, 0, stream>>>(dd2, dec_w3, dec_b3, (float*)d_out);
}